// Round 1
// baseline (2455.958 us; speedup 1.0000x reference)
//
#include <hip/hip_runtime.h>
#include <hip/hip_bf16.h>

#define CDIM 384
#define NHEADS 12
#define HDIM 32
#define HIDDEN 1536
#define BBATCH 32
#define HH 28
#define WW 28
#define NTOK 784
#define BN (BBATCH * NTOK)   // 25088
#define LN_EPS 1e-5f
#define ATT_SCALE 0.17677669529663687f

typedef __hip_bfloat16 bf16;

__device__ __forceinline__ float ldf(const float* p) { return *p; }
__device__ __forceinline__ float ldf(const bf16* p) { return __bfloat162float(*p); }
__device__ __forceinline__ void stf(float* p, float v) { *p = v; }
__device__ __forceinline__ void stf(bf16* p, float v) { *p = __float2bfloat16(v); }

// ---------------- dwconv1: x (B,C,H,W) -> xt (B,N,C) with residual ----------------
__global__ __launch_bounds__(256) void dwconv_nchw_to_bnc(
    const float* __restrict__ x, const float* __restrict__ w,
    const float* __restrict__ bias, float* __restrict__ xt)
{
    size_t g = (size_t)blockIdx.x * 256 + threadIdx.x;
    if (g >= (size_t)BN * CDIM) return;
    int c = (int)(g % CDIM);
    size_t r = g / CDIM;           // token index b*N + n
    int n = (int)(r % NTOK);
    int b = (int)(r / NTOK);
    int h = n / WW, wcol = n % WW;
    const float* xp = x + ((size_t)b * CDIM + c) * NTOK;
    const float* wp = w + c * 9;
    float s = 0.f;
#pragma unroll
    for (int di = -1; di <= 1; di++) {
#pragma unroll
        for (int dj = -1; dj <= 1; dj++) {
            int hh = h + di, ww2 = wcol + dj;
            if (hh >= 0 && hh < HH && ww2 >= 0 && ww2 < WW)
                s += wp[(di + 1) * 3 + (dj + 1)] * xp[hh * WW + ww2];
        }
    }
    xt[g] = xp[h * WW + wcol] + s + bias[c];
}

// ---------------- dwconv2 in (B,N,C) layout, with residual ----------------
__global__ __launch_bounds__(256) void dwconv_bnc(
    const float* __restrict__ xin, const float* __restrict__ w,
    const float* __restrict__ bias, float* __restrict__ xout)
{
    size_t g = (size_t)blockIdx.x * 256 + threadIdx.x;
    if (g >= (size_t)BN * CDIM) return;
    int c = (int)(g % CDIM);
    size_t r = g / CDIM;
    int n = (int)(r % NTOK);
    int b = (int)(r / NTOK);
    int h = n / WW, wcol = n % WW;
    const float* wp = w + c * 9;
    const float* base = xin + (size_t)b * NTOK * CDIM;
    float s = 0.f;
#pragma unroll
    for (int di = -1; di <= 1; di++) {
#pragma unroll
        for (int dj = -1; dj <= 1; dj++) {
            int hh = h + di, ww2 = wcol + dj;
            if (hh >= 0 && hh < HH && ww2 >= 0 && ww2 < WW)
                s += wp[(di + 1) * 3 + (dj + 1)] * base[(size_t)(hh * WW + ww2) * CDIM + c];
        }
    }
    xout[g] = xin[g] + s + bias[c];
}

// ---------------- LayerNorm over C=384, one wave (64 lanes) per token ----------------
__global__ __launch_bounds__(256) void layernorm_k(
    const float* __restrict__ in, const float* __restrict__ g,
    const float* __restrict__ b, float* __restrict__ out)
{
    int wid = threadIdx.x >> 6;
    int lane = threadIdx.x & 63;
    size_t r = (size_t)blockIdx.x * 4 + wid;
    const float* row = in + r * CDIM;
    float v[6];
    float s = 0.f;
#pragma unroll
    for (int j = 0; j < 6; j++) { v[j] = row[lane + 64 * j]; s += v[j]; }
#pragma unroll
    for (int off = 32; off >= 1; off >>= 1) s += __shfl_xor(s, off);
    float mu = s * (1.f / CDIM);
    float q = 0.f;
#pragma unroll
    for (int j = 0; j < 6; j++) { float d = v[j] - mu; q += d * d; }
#pragma unroll
    for (int off = 32; off >= 1; off >>= 1) q += __shfl_xor(q, off);
    float rs = rsqrtf(q * (1.f / CDIM) + LN_EPS);
    float* orow = out + r * CDIM;
#pragma unroll
    for (int j = 0; j < 6; j++) {
        int c = lane + 64 * j;
        orow[c] = (v[j] - mu) * rs * g[c] + b[c];
    }
}

// ---------------- Generic tiled GEMM: C = A(rows x K) * Bw(M x K)^T [+bias][+res][gelu] ----
template <typename TA, typename TO, int ACT, bool RES>
__global__ __launch_bounds__(256) void gemm_bt(
    const TA* __restrict__ A, const float* __restrict__ Bw,
    const float* __restrict__ bias, const float* __restrict__ res,
    TO* __restrict__ Co, int rows, int K, int M)
{
    __shared__ float As[16][65];
    __shared__ float Bs[16][65];
    const int tid = threadIdx.x;
    const int r0 = blockIdx.y * 64;
    const int m0 = blockIdx.x * 64;
    const int ar = tid >> 2;          // 0..63
    const int ak = (tid & 3) * 4;     // 0,4,8,12
    const int tx = tid & 15, ty = tid >> 4;
    float acc[4][4] = {};
    for (int k0 = 0; k0 < K; k0 += 16) {
        const TA* ap = A + (size_t)(r0 + ar) * K + k0 + ak;
        float a0 = ldf(ap + 0), a1 = ldf(ap + 1), a2 = ldf(ap + 2), a3 = ldf(ap + 3);
        As[ak + 0][ar] = a0; As[ak + 1][ar] = a1; As[ak + 2][ar] = a2; As[ak + 3][ar] = a3;
        const float* bp = Bw + (size_t)(m0 + ar) * K + k0 + ak;
        float b0 = bp[0], b1 = bp[1], b2 = bp[2], b3 = bp[3];
        Bs[ak + 0][ar] = b0; Bs[ak + 1][ar] = b1; Bs[ak + 2][ar] = b2; Bs[ak + 3][ar] = b3;
        __syncthreads();
#pragma unroll
        for (int kk = 0; kk < 16; kk++) {
            float av[4], bv[4];
#pragma unroll
            for (int i = 0; i < 4; i++) av[i] = As[kk][ty * 4 + i];
#pragma unroll
            for (int j = 0; j < 4; j++) bv[j] = Bs[kk][tx * 4 + j];
#pragma unroll
            for (int i = 0; i < 4; i++)
#pragma unroll
                for (int j = 0; j < 4; j++) acc[i][j] += av[i] * bv[j];
        }
        __syncthreads();
    }
#pragma unroll
    for (int i = 0; i < 4; i++) {
        size_t r = r0 + ty * 4 + i;
#pragma unroll
        for (int j = 0; j < 4; j++) {
            int m = m0 + tx * 4 + j;
            float v = acc[i][j];
            if (bias) v += bias[m];
            if (RES) v += res[r * (size_t)M + m];
            if (ACT == 1) v = 0.5f * v * (1.f + erff(v * 0.70710678118f));
            stf(Co + r * (size_t)M + m, v);
        }
    }
}

// ---------------- channel attention: attn[b,h,d,e] = softmax_e(SCALE * sum_n k*v) ------
__global__ __launch_bounds__(256) void attn_k(
    const bf16* __restrict__ qkv, float* __restrict__ attn)
{
    int bh = blockIdx.x;
    int b = bh / NHEADS, h = bh % NHEADS;
    __shared__ float ks[64][32];
    __shared__ float vs[64][32];
    __shared__ float sm[32][33];
    int tid = threadIdx.x;
    int d = tid >> 3, e0 = (tid & 7) * 4;
    float acc[4] = {0.f, 0.f, 0.f, 0.f};
    for (int n0 = 0; n0 < NTOK; n0 += 64) {
#pragma unroll
        for (int i = 0; i < 8; i++) {
            int idx = tid + i * 256;   // 0..2047
            int nn = idx >> 5, cc = idx & 31;
            int n = n0 + nn;
            float kv = 0.f, vv = 0.f;
            if (n < NTOK) {
                size_t base = ((size_t)b * NTOK + n) * (3 * CDIM);
                kv = ATT_SCALE * __bfloat162float(qkv[base + CDIM + h * HDIM + cc]);
                vv = __bfloat162float(qkv[base + 2 * CDIM + h * HDIM + cc]);
            }
            ks[nn][cc] = kv; vs[nn][cc] = vv;
        }
        __syncthreads();
#pragma unroll 8
        for (int nn = 0; nn < 64; nn++) {
            float kd = ks[nn][d];
#pragma unroll
            for (int j = 0; j < 4; j++) acc[j] += kd * vs[nn][e0 + j];
        }
        __syncthreads();
    }
#pragma unroll
    for (int j = 0; j < 4; j++) sm[d][e0 + j] = acc[j];
    __syncthreads();
    if (tid < 32) {
        float mx = -1e30f;
#pragma unroll
        for (int e = 0; e < 32; e++) mx = fmaxf(mx, sm[tid][e]);
        float ssum = 0.f;
        float ex[32];
#pragma unroll
        for (int e = 0; e < 32; e++) { ex[e] = expf(sm[tid][e] - mx); ssum += ex[e]; }
        float inv = 1.f / ssum;
        float* arow = attn + ((size_t)bh * 32 + tid) * 32;
#pragma unroll
        for (int e = 0; e < 32; e++) arow[e] = ex[e] * inv;
    }
}

// ---------------- apply attention: out[b,n,c=h*32+d] = sum_e attn[b,h,d,e]*q[b,n,h,e] --
__global__ __launch_bounds__(384) void apply_attn_k(
    const bf16* __restrict__ qkv, const float* __restrict__ attn,
    float* __restrict__ out)
{
    int b = blockIdx.x;
    int chunk = blockIdx.y;            // 8 chunks of 98 tokens
    __shared__ float at[NHEADS][32][33];
    __shared__ float qs[CDIM];
    int tid = threadIdx.x;             // 0..383
#pragma unroll
    for (int i = 0; i < 32; i++) {
        int idx = tid + i * 384;       // 0..12287
        int hh = idx >> 10, dd = (idx >> 5) & 31, ee = idx & 31;
        at[hh][dd][ee] = attn[((size_t)(b * NHEADS + hh) * 32 + dd) * 32 + ee];
    }
    int h = tid >> 5, d = tid & 31;
    for (int t = 0; t < 98; t++) {
        int n = chunk * 98 + t;
        size_t base = ((size_t)b * NTOK + n) * (3 * CDIM);
        __syncthreads();
        qs[tid] = __bfloat162float(qkv[base + tid]);   // q slice
        __syncthreads();
        float s = 0.f;
#pragma unroll
        for (int e = 0; e < 32; e++) s += at[h][d][e] * qs[h * 32 + e];
        out[((size_t)b * NTOK + n) * CDIM + tid] = s;
    }
}

// ---------------- final transpose: (B,N,C) -> (B,C,H,W) ----------------
__global__ __launch_bounds__(256) void transpose_out(
    const float* __restrict__ in, float* __restrict__ out)
{
    __shared__ float t[32][33];
    int b = blockIdx.z;
    int n0 = blockIdx.y * 32;
    int c0 = blockIdx.x * 32;
    int tx = threadIdx.x, ty = threadIdx.y;   // 32 x 8
    for (int i = ty; i < 32; i += 8) {
        int n = n0 + i;
        if (n < NTOK) t[i][tx] = in[((size_t)b * NTOK + n) * CDIM + c0 + tx];
    }
    __syncthreads();
    for (int i = ty; i < 32; i += 8) {
        int c = c0 + i;
        int n = n0 + tx;
        if (n < NTOK) out[((size_t)b * CDIM + c) * NTOK + n] = t[tx][i];
    }
}

extern "C" void kernel_launch(void* const* d_in, const int* in_sizes, int n_in,
                              void* d_out, int out_size, void* d_ws, size_t ws_size,
                              hipStream_t stream) {
    const float* x      = (const float*)d_in[0];
    const float* cpe1_w = (const float*)d_in[1];
    const float* cpe1_b = (const float*)d_in[2];
    const float* n1g    = (const float*)d_in[3];
    const float* n1b    = (const float*)d_in[4];
    const float* qkv_w  = (const float*)d_in[5];
    const float* proj_w = (const float*)d_in[6];
    const float* proj_b = (const float*)d_in[7];
    const float* cpe2_w = (const float*)d_in[8];
    const float* cpe2_b = (const float*)d_in[9];
    const float* n2g    = (const float*)d_in[10];
    const float* n2b    = (const float*)d_in[11];
    const float* fc1_w  = (const float*)d_in[12];
    const float* fc1_b  = (const float*)d_in[13];
    const float* fc2_w  = (const float*)d_in[14];
    const float* fc2_b  = (const float*)d_in[15];

    const size_t A = (size_t)BN * CDIM;        // 9,633,792
    float* ws = (float*)d_ws;
    float* xt       = ws;                      // [0, A)       token-major stream
    float* cur      = ws + A;                  // [A, 2A)      LN1 out; later x3
    bf16*  qkvb     = (bf16*)(ws + 2 * A);     // bf16, 3A elems -> [2A, 3.5A)
    float* attn_out = ws + (A * 7) / 2;        // [3.5A, 4.5A)
    float* attnm    = ws + (A * 9) / 2;        // [4.5A, +0.4M)
    float* x3       = cur;                     // phase 2 reuse
    float* yln      = ws + 2 * A;              // [2A, 3A)     (qkv dead)
    bf16*  h1       = (bf16*)(ws + 3 * A);     // bf16, 4A elems -> [3A, 5A)
    float* finalb   = ws + 2 * A;              // reuse yln slot (dead after fc1)

    const int nblk_elem = (int)((A + 255) / 256);

    // 1. cpe1 + residual, NCHW -> (B,N,C)
    dwconv_nchw_to_bnc<<<nblk_elem, 256, 0, stream>>>(x, cpe1_w, cpe1_b, xt);
    // 2. LN1
    layernorm_k<<<BN / 4, 256, 0, stream>>>(xt, n1g, n1b, cur);
    // 3. qkv GEMM (out bf16)
    gemm_bt<float, bf16, 0, false><<<dim3(1152 / 64, BN / 64), 256, 0, stream>>>(
        cur, qkv_w, nullptr, nullptr, qkvb, BN, 384, 1152);
    // 4. channel attention matrices + softmax
    attn_k<<<BBATCH * NHEADS, 256, 0, stream>>>(qkvb, attnm);
    // 5. apply attention to q
    apply_attn_k<<<dim3(BBATCH, 8), 384, 0, stream>>>(qkvb, attnm, attn_out);
    // 6. proj GEMM + bias + residual (in-place into xt -> x2)
    gemm_bt<float, float, 0, true><<<dim3(384 / 64, BN / 64), 256, 0, stream>>>(
        attn_out, proj_w, proj_b, xt, xt, BN, 384, 384);
    // 7. cpe2 + residual in (B,N,C)
    dwconv_bnc<<<nblk_elem, 256, 0, stream>>>(xt, cpe2_w, cpe2_b, x3);
    // 8. LN2
    layernorm_k<<<BN / 4, 256, 0, stream>>>(x3, n2g, n2b, yln);
    // 9. fc1 + bias + exact GELU (out bf16)
    gemm_bt<float, bf16, 1, false><<<dim3(1536 / 64, BN / 64), 256, 0, stream>>>(
        yln, fc1_w, fc1_b, nullptr, h1, BN, 384, 1536);
    // 10. fc2 + bias + residual(x3)
    gemm_bt<bf16, float, 0, true><<<dim3(384 / 64, BN / 64), 256, 0, stream>>>(
        h1, fc2_w, fc2_b, x3, finalb, BN, 1536, 384);
    // 11. (B,N,C) -> (B,C,H,W)
    transpose_out<<<dim3(CDIM / 32, (NTOK + 31) / 32, BBATCH), dim3(32, 8), 0, stream>>>(
        finalb, (float*)d_out);
}

// Round 2
// 935.387 us; speedup vs baseline: 2.6256x; 2.6256x over previous
//
#include <hip/hip_runtime.h>
#include <hip/hip_bf16.h>

#define CDIM 384
#define NHEADS 12
#define HDIM 32
#define HIDDEN 1536
#define BBATCH 32
#define HH 28
#define WW 28
#define NTOK 784
#define BN (BBATCH * NTOK)   // 25088
#define LN_EPS 1e-5f
#define ATT_SCALE 0.17677669529663687f

typedef __hip_bfloat16 bf16;
typedef __attribute__((ext_vector_type(8))) short bf16x8;
typedef __attribute__((ext_vector_type(4))) float f32x4;

__device__ __forceinline__ float ldf(const float* p) { return *p; }
__device__ __forceinline__ float ldf(const bf16* p) { return __bfloat162float(*p); }
__device__ __forceinline__ void stf(float* p, float v) { *p = v; }
__device__ __forceinline__ void stf(bf16* p, float v) { *p = __float2bfloat16(v); }

__device__ __forceinline__ void gload16(const void* g, void* l) {
    __builtin_amdgcn_global_load_lds(
        (const __attribute__((address_space(1))) unsigned int*)g,
        (__attribute__((address_space(3))) unsigned int*)l, 16, 0, 0);
}

// ---------------- fp32 -> bf16 weight conversion ----------------
__global__ __launch_bounds__(256) void f2b_k(const float* __restrict__ src,
                                             bf16* __restrict__ dst, int n)
{
    int i = blockIdx.x * 256 + threadIdx.x;
    if (i < n) dst[i] = __float2bfloat16(src[i]);
}

// ---------------- dwconv1: x (B,C,H,W) -> xt (B,N,C) with residual ----------------
__global__ __launch_bounds__(256) void dwconv_nchw_to_bnc(
    const float* __restrict__ x, const float* __restrict__ w,
    const float* __restrict__ bias, float* __restrict__ xt)
{
    size_t g = (size_t)blockIdx.x * 256 + threadIdx.x;
    if (g >= (size_t)BN * CDIM) return;
    int c = (int)(g % CDIM);
    size_t r = g / CDIM;           // token index b*N + n
    int n = (int)(r % NTOK);
    int b = (int)(r / NTOK);
    int h = n / WW, wcol = n % WW;
    const float* xp = x + ((size_t)b * CDIM + c) * NTOK;
    const float* wp = w + c * 9;
    float s = 0.f;
#pragma unroll
    for (int di = -1; di <= 1; di++) {
#pragma unroll
        for (int dj = -1; dj <= 1; dj++) {
            int hh = h + di, ww2 = wcol + dj;
            if (hh >= 0 && hh < HH && ww2 >= 0 && ww2 < WW)
                s += wp[(di + 1) * 3 + (dj + 1)] * xp[hh * WW + ww2];
        }
    }
    xt[g] = xp[h * WW + wcol] + s + bias[c];
}

// ---------------- dwconv2 in (B,N,C) layout, with residual ----------------
__global__ __launch_bounds__(256) void dwconv_bnc(
    const float* __restrict__ xin, const float* __restrict__ w,
    const float* __restrict__ bias, float* __restrict__ xout)
{
    size_t g = (size_t)blockIdx.x * 256 + threadIdx.x;
    if (g >= (size_t)BN * CDIM) return;
    int c = (int)(g % CDIM);
    size_t r = g / CDIM;
    int n = (int)(r % NTOK);
    int b = (int)(r / NTOK);
    int h = n / WW, wcol = n % WW;
    const float* wp = w + c * 9;
    const float* base = xin + (size_t)b * NTOK * CDIM;
    float s = 0.f;
#pragma unroll
    for (int di = -1; di <= 1; di++) {
#pragma unroll
        for (int dj = -1; dj <= 1; dj++) {
            int hh = h + di, ww2 = wcol + dj;
            if (hh >= 0 && hh < HH && ww2 >= 0 && ww2 < WW)
                s += wp[(di + 1) * 3 + (dj + 1)] * base[(size_t)(hh * WW + ww2) * CDIM + c];
        }
    }
    xout[g] = xin[g] + s + bias[c];
}

// ---------------- LayerNorm over C=384, one wave per token; TO = float or bf16 ----------
template <typename TO>
__global__ __launch_bounds__(256) void layernorm_k(
    const float* __restrict__ in, const float* __restrict__ g,
    const float* __restrict__ b, TO* __restrict__ out)
{
    int wid = threadIdx.x >> 6;
    int lane = threadIdx.x & 63;
    size_t r = (size_t)blockIdx.x * 4 + wid;
    const float* row = in + r * CDIM;
    float v[6];
    float s = 0.f;
#pragma unroll
    for (int j = 0; j < 6; j++) { v[j] = row[lane + 64 * j]; s += v[j]; }
#pragma unroll
    for (int off = 32; off >= 1; off >>= 1) s += __shfl_xor(s, off);
    float mu = s * (1.f / CDIM);
    float q = 0.f;
#pragma unroll
    for (int j = 0; j < 6; j++) { float d = v[j] - mu; q += d * d; }
#pragma unroll
    for (int off = 32; off >= 1; off >>= 1) q += __shfl_xor(q, off);
    float rs = rsqrtf(q * (1.f / CDIM) + LN_EPS);
    TO* orow = out + r * CDIM;
#pragma unroll
    for (int j = 0; j < 6; j++) {
        int c = lane + 64 * j;
        stf(&orow[c], (v[j] - mu) * rs * g[c] + b[c]);
    }
}

// ---------------- MFMA GEMM: Co = A(rows x K) * Bw(M x K)^T [+bias][+res][gelu] -------
// A, Bw in bf16 (as short). 128x128 tile, 4 waves, 16x16x32 bf16 MFMA, BK=32.
// LDS granule swizzle: slot(row,quad) = row*4 + (quad ^ ((row>>1)&3))  -> 2-way
// (free) bank aliasing on ds_read_b128 fragment reads while keeping the
// global_load_lds wave-uniform-base+lane*16 contiguity requirement.
template <int ACT, bool RES, typename TO>
__global__ __launch_bounds__(256) void gemm_mfma(
    const short* __restrict__ Abf, const short* __restrict__ Bw,
    const float* __restrict__ bias, const float* __restrict__ res,
    TO* __restrict__ Co, int K, int M)
{
    __shared__ short As[4096];   // 128 rows x 32 cols bf16, swizzled granules
    __shared__ short Bs[4096];
    const int tid = threadIdx.x;
    const int wid = tid >> 6, lane = tid & 63;
    const int wrow = wid >> 1, wcol = wid & 1;
    const int quad = lane >> 4, lr = lane & 15;
    const int r0 = blockIdx.y * 128, m0 = blockIdx.x * 128;

    // staging: 8 x 1KB instructions per tile; wave w issues insts {2w, 2w+1}
    const int inst0 = wid * 2;
    const int row0 = inst0 * 16 + (lane >> 2);
    const int row1 = row0 + 16;
    const int q0 = (lane & 3) ^ ((row0 >> 1) & 3);
    const int q1 = (lane & 3) ^ ((row1 >> 1) & 3);
    const short* gA0 = Abf + (size_t)(r0 + row0) * K + q0 * 8;
    const short* gA1 = Abf + (size_t)(r0 + row1) * K + q1 * 8;
    const short* gB0 = Bw + (size_t)(m0 + row0) * K + q0 * 8;
    const short* gB1 = Bw + (size_t)(m0 + row1) * K + q1 * 8;
    short* lA0 = As + inst0 * 512;
    short* lA1 = lA0 + 512;
    short* lB0 = Bs + inst0 * 512;
    short* lB1 = lB0 + 512;

    // fragment LDS addresses (loop-invariant)
    const short* fA[4];
    const short* fB[4];
#pragma unroll
    for (int i = 0; i < 4; i++) {
        int ar = wrow * 64 + i * 16 + lr;
        fA[i] = As + (ar * 4 + (quad ^ ((ar >> 1) & 3))) * 8;
        int br = wcol * 64 + i * 16 + lr;
        fB[i] = Bs + (br * 4 + (quad ^ ((br >> 1) & 3))) * 8;
    }

    f32x4 acc[4][4] = {};

    for (int k0 = 0; k0 < K; k0 += 32) {
        gload16(gA0, lA0); gload16(gA1, lA1);
        gload16(gB0, lB0); gload16(gB1, lB1);
        gA0 += 32; gA1 += 32; gB0 += 32; gB1 += 32;
        __syncthreads();               // drains vmcnt -> LDS tile ready
        bf16x8 av[4], bv[4];
#pragma unroll
        for (int i = 0; i < 4; i++) {
            av[i] = *(const bf16x8*)fA[i];
            bv[i] = *(const bf16x8*)fB[i];
        }
#pragma unroll
        for (int i = 0; i < 4; i++)
#pragma unroll
            for (int j = 0; j < 4; j++)
                acc[i][j] = __builtin_amdgcn_mfma_f32_16x16x32_bf16(
                    av[i], bv[j], acc[i][j], 0, 0, 0);
        __syncthreads();               // protect LDS from next iter's stores
    }

    // epilogue: D[m][n] -> m = quad*4 + reg, n = lane&15 (m89-verified layout)
#pragma unroll
    for (int i = 0; i < 4; i++) {
        int gr = r0 + wrow * 64 + i * 16 + quad * 4;
#pragma unroll
        for (int j = 0; j < 4; j++) {
            int gc = m0 + wcol * 64 + j * 16 + lr;
            float bb = bias ? bias[gc] : 0.f;
#pragma unroll
            for (int rreg = 0; rreg < 4; rreg++) {
                size_t idx = (size_t)(gr + rreg) * M + gc;
                float v = acc[i][j][rreg] + bb;
                if (RES) v += res[idx];
                if (ACT == 1) v = 0.5f * v * (1.f + erff(v * 0.70710678118f));
                stf(&Co[idx], v);
            }
        }
    }
}

// ---------------- channel attention: attn[b,h,d,e] = softmax_e(SCALE * sum_n k*v) ------
__global__ __launch_bounds__(256) void attn_k(
    const bf16* __restrict__ qkv, float* __restrict__ attn)
{
    int bh = blockIdx.x;
    int b = bh / NHEADS, h = bh % NHEADS;
    __shared__ float ks[64][32];
    __shared__ float vs[64][32];
    __shared__ float sm[32][33];
    int tid = threadIdx.x;
    int d = tid >> 3, e0 = (tid & 7) * 4;
    float acc[4] = {0.f, 0.f, 0.f, 0.f};
    for (int n0 = 0; n0 < NTOK; n0 += 64) {
#pragma unroll
        for (int i = 0; i < 8; i++) {
            int idx = tid + i * 256;   // 0..2047
            int nn = idx >> 5, cc = idx & 31;
            int n = n0 + nn;
            float kv = 0.f, vv = 0.f;
            if (n < NTOK) {
                size_t base = ((size_t)b * NTOK + n) * (3 * CDIM);
                kv = ATT_SCALE * __bfloat162float(qkv[base + CDIM + h * HDIM + cc]);
                vv = __bfloat162float(qkv[base + 2 * CDIM + h * HDIM + cc]);
            }
            ks[nn][cc] = kv; vs[nn][cc] = vv;
        }
        __syncthreads();
#pragma unroll 8
        for (int nn = 0; nn < 64; nn++) {
            float kd = ks[nn][d];
#pragma unroll
            for (int j = 0; j < 4; j++) acc[j] += kd * vs[nn][e0 + j];
        }
        __syncthreads();
    }
#pragma unroll
    for (int j = 0; j < 4; j++) sm[d][e0 + j] = acc[j];
    __syncthreads();
    if (tid < 32) {
        float mx = -1e30f;
#pragma unroll
        for (int e = 0; e < 32; e++) mx = fmaxf(mx, sm[tid][e]);
        float ssum = 0.f;
        float ex[32];
#pragma unroll
        for (int e = 0; e < 32; e++) { ex[e] = expf(sm[tid][e] - mx); ssum += ex[e]; }
        float inv = 1.f / ssum;
        float* arow = attn + ((size_t)bh * 32 + tid) * 32;
#pragma unroll
        for (int e = 0; e < 32; e++) arow[e] = ex[e] * inv;
    }
}

// ---------------- apply attention: out[b,n,c=h*32+d] = sum_e attn[b,h,d,e]*q[b,n,h,e] --
__global__ __launch_bounds__(384) void apply_attn_k(
    const bf16* __restrict__ qkv, const float* __restrict__ attn,
    bf16* __restrict__ out)
{
    int b = blockIdx.x;
    int chunk = blockIdx.y;            // 8 chunks of 98 tokens
    __shared__ float at[NHEADS][32][33];
    __shared__ float qs[CDIM];
    int tid = threadIdx.x;             // 0..383
#pragma unroll
    for (int i = 0; i < 32; i++) {
        int idx = tid + i * 384;       // 0..12287
        int hh = idx >> 10, dd = (idx >> 5) & 31, ee = idx & 31;
        at[hh][dd][ee] = attn[((size_t)(b * NHEADS + hh) * 32 + dd) * 32 + ee];
    }
    int h = tid >> 5, d = tid & 31;
    for (int t = 0; t < 98; t++) {
        int n = chunk * 98 + t;
        size_t base = ((size_t)b * NTOK + n) * (3 * CDIM);
        __syncthreads();
        qs[tid] = __bfloat162float(qkv[base + tid]);   // q slice
        __syncthreads();
        float s = 0.f;
#pragma unroll
        for (int e = 0; e < 32; e++) s += at[h][d][e] * qs[h * 32 + e];
        out[((size_t)b * NTOK + n) * CDIM + tid] = __float2bfloat16(s);
    }
}

// ---------------- final transpose: (B,N,C) -> (B,C,H,W) ----------------
__global__ __launch_bounds__(256) void transpose_out(
    const float* __restrict__ in, float* __restrict__ out)
{
    __shared__ float t[32][33];
    int b = blockIdx.z;
    int n0 = blockIdx.y * 32;
    int c0 = blockIdx.x * 32;
    int tx = threadIdx.x, ty = threadIdx.y;   // 32 x 8
    for (int i = ty; i < 32; i += 8) {
        int n = n0 + i;
        if (n < NTOK) t[i][tx] = in[((size_t)b * NTOK + n) * CDIM + c0 + tx];
    }
    __syncthreads();
    for (int i = ty; i < 32; i += 8) {
        int c = c0 + i;
        int n = n0 + tx;
        if (n < NTOK) out[((size_t)b * CDIM + c) * NTOK + n] = t[tx][i];
    }
}

extern "C" void kernel_launch(void* const* d_in, const int* in_sizes, int n_in,
                              void* d_out, int out_size, void* d_ws, size_t ws_size,
                              hipStream_t stream) {
    const float* x      = (const float*)d_in[0];
    const float* cpe1_w = (const float*)d_in[1];
    const float* cpe1_b = (const float*)d_in[2];
    const float* n1g    = (const float*)d_in[3];
    const float* n1b    = (const float*)d_in[4];
    const float* qkv_w  = (const float*)d_in[5];
    const float* proj_w = (const float*)d_in[6];
    const float* proj_b = (const float*)d_in[7];
    const float* cpe2_w = (const float*)d_in[8];
    const float* cpe2_b = (const float*)d_in[9];
    const float* n2g    = (const float*)d_in[10];
    const float* n2b    = (const float*)d_in[11];
    const float* fc1_w  = (const float*)d_in[12];
    const float* fc1_b  = (const float*)d_in[13];
    const float* fc2_w  = (const float*)d_in[14];
    const float* fc2_b  = (const float*)d_in[15];

    const size_t A = (size_t)BN * CDIM;        // 9,633,792
    const size_t HA = A / 2;

    // bf16 weights live at the front of ws (1,769,472 shorts = 884,736 floats)
    bf16* wqkv  = (bf16*)d_ws;                 // 1152*384 = 442368
    bf16* wproj = wqkv + 442368;               // 384*384  = 147456
    bf16* wfc1  = wproj + 147456;              // 1536*384 = 589824
    bf16* wfc2  = wfc1 + 589824;               // 384*1536 = 589824
    float* base = (float*)d_ws + 884736;

    float* xt        = base;                   // [0, A)        residual stream
    bf16*  curb      = (bf16*)(base + A);      // [A, 1.5A)     LN1 out (bf16)
    bf16*  ylnb      = (bf16*)(base + A);      // phase-2 reuse LN2 out (bf16)
    bf16*  qkvb      = (bf16*)(base + A + HA); // [1.5A, 3A)    qkv (bf16, 3A elems)
    float* x3        = base + A + HA;          // phase-2 reuse [1.5A, 2.5A)
    bf16*  h1        = (bf16*)(base + A + HA + A); // [2.5A, 4.5A) fc1 out (bf16, 4A elems)
    float* attnm     = base + 3 * A;           // [3A, +393216)
    bf16*  attn_outb = (bf16*)(base + 3 * A + 393216); // 0.5A floats
    float* finalb    = base;                   // xt region reuse
    // peak = 884736 + 4.5A floats = 176.9 MB (< round-0 proven ws >= 192.7 MB)

    const int nblk_elem = (int)((A + 255) / 256);

    // 0. weight conversion fp32 -> bf16
    f2b_k<<<(442368 + 255) / 256, 256, 0, stream>>>(qkv_w, wqkv, 442368);
    f2b_k<<<(147456 + 255) / 256, 256, 0, stream>>>(proj_w, wproj, 147456);
    f2b_k<<<(589824 + 255) / 256, 256, 0, stream>>>(fc1_w, wfc1, 589824);
    f2b_k<<<(589824 + 255) / 256, 256, 0, stream>>>(fc2_w, wfc2, 589824);

    // 1. cpe1 + residual, NCHW -> (B,N,C)
    dwconv_nchw_to_bnc<<<nblk_elem, 256, 0, stream>>>(x, cpe1_w, cpe1_b, xt);
    // 2. LN1 -> bf16
    layernorm_k<bf16><<<BN / 4, 256, 0, stream>>>(xt, n1g, n1b, curb);
    // 3. qkv GEMM (bf16 MFMA, out bf16)
    gemm_mfma<0, false, bf16><<<dim3(1152 / 128, BN / 128), 256, 0, stream>>>(
        (const short*)curb, (const short*)wqkv, nullptr, nullptr, qkvb, 384, 1152);
    // 4. channel attention matrices + softmax
    attn_k<<<BBATCH * NHEADS, 256, 0, stream>>>(qkvb, attnm);
    // 5. apply attention to q (out bf16)
    apply_attn_k<<<dim3(BBATCH, 8), 384, 0, stream>>>(qkvb, attnm, attn_outb);
    // 6. proj GEMM + bias + residual (in-place into xt)
    gemm_mfma<0, true, float><<<dim3(384 / 128, BN / 128), 256, 0, stream>>>(
        (const short*)attn_outb, (const short*)wproj, proj_b, xt, xt, 384, 384);
    // 7. cpe2 + residual in (B,N,C)
    dwconv_bnc<<<nblk_elem, 256, 0, stream>>>(xt, cpe2_w, cpe2_b, x3);
    // 8. LN2 -> bf16
    layernorm_k<bf16><<<BN / 4, 256, 0, stream>>>(x3, n2g, n2b, ylnb);
    // 9. fc1 + bias + exact GELU (out bf16)
    gemm_mfma<1, false, bf16><<<dim3(1536 / 128, BN / 128), 256, 0, stream>>>(
        (const short*)ylnb, (const short*)wfc1, fc1_b, nullptr, h1, 384, 1536);
    // 10. fc2 + bias + residual(x3)
    gemm_mfma<0, true, float><<<dim3(384 / 128, BN / 128), 256, 0, stream>>>(
        (const short*)h1, (const short*)wfc2, fc2_b, x3, finalb, 1536, 384);
    // 11. (B,N,C) -> (B,C,H,W)
    transpose_out<<<dim3(CDIM / 32, (NTOK + 31) / 32, BBATCH), dim3(32, 8), 0, stream>>>(
        finalb, (float*)d_out);
}

// Round 3
// 595.734 us; speedup vs baseline: 4.1226x; 1.5701x over previous
//
#include <hip/hip_runtime.h>
#include <hip/hip_bf16.h>

#define CDIM 384
#define NHEADS 12
#define HDIM 32
#define HIDDEN 1536
#define BBATCH 32
#define HH 28
#define WW 28
#define NTOK 784
#define BN (BBATCH * NTOK)   // 25088
#define LN_EPS 1e-5f
#define ATT_SCALE 0.17677669529663687f

typedef __hip_bfloat16 bf16;
typedef __attribute__((ext_vector_type(8))) short bf16x8;
typedef __attribute__((ext_vector_type(4))) float f32x4;

__device__ __forceinline__ float ldf(const float* p) { return *p; }
__device__ __forceinline__ float ldf(const bf16* p) { return __bfloat162float(*p); }
__device__ __forceinline__ void stf(float* p, float v) { *p = v; }
__device__ __forceinline__ void stf(bf16* p, float v) { *p = __float2bfloat16(v); }

__device__ __forceinline__ void gload16(const void* g, void* l) {
    __builtin_amdgcn_global_load_lds(
        (const __attribute__((address_space(1))) unsigned int*)g,
        (__attribute__((address_space(3))) unsigned int*)l, 16, 0, 0);
}

// ---------------- fp32 -> bf16 weight conversion ----------------
__global__ __launch_bounds__(256) void f2b_k(const float* __restrict__ src,
                                             bf16* __restrict__ dst, int n)
{
    int i = blockIdx.x * 256 + threadIdx.x;
    if (i < n) dst[i] = __float2bfloat16(src[i]);
}

// ---------------- dwconv1 pass A: per-(b,c) plane conv in NCHW, coalesced ----------------
// y = x + conv3x3(x) + bias, all in NCHW layout. One block per (b,c) plane.
__global__ __launch_bounds__(256) void dwconv_nchw_plane(
    const float* __restrict__ x, const float* __restrict__ w,
    const float* __restrict__ bias, float* __restrict__ y)
{
    __shared__ float sm[NTOK];
    int bc = blockIdx.x;                    // b*CDIM + c
    int c = bc % CDIM;
    const float* xp = x + (size_t)bc * NTOK;
    int tid = threadIdx.x;
#pragma unroll
    for (int i = 0; i < 4; i++) {
        int p = tid + i * 256;
        if (p < NTOK) sm[p] = xp[p];
    }
    __syncthreads();
    const float* wp = w + c * 9;            // wave-uniform -> scalar loads
    float w00 = wp[0], w01 = wp[1], w02 = wp[2];
    float w10 = wp[3], w11 = wp[4], w12 = wp[5];
    float w20 = wp[6], w21 = wp[7], w22 = wp[8];
    float bc_ = bias[c];
    float* yp = y + (size_t)bc * NTOK;
#pragma unroll
    for (int i = 0; i < 4; i++) {
        int p = tid + i * 256;
        if (p >= NTOK) break;
        int h = p / WW, wcol = p % WW;
        bool hm = h > 0, hp = h < HH - 1, wm = wcol > 0, wpv = wcol < WW - 1;
        float s = w11 * sm[p];
        if (hm)        s += w01 * sm[p - WW];
        if (hp)        s += w21 * sm[p + WW];
        if (wm)        s += w10 * sm[p - 1];
        if (wpv)       s += w12 * sm[p + 1];
        if (hm && wm)  s += w00 * sm[p - WW - 1];
        if (hm && wpv) s += w02 * sm[p - WW + 1];
        if (hp && wm)  s += w20 * sm[p + WW - 1];
        if (hp && wpv) s += w22 * sm[p + WW + 1];
        yp[p] = sm[p] + s + bc_;
    }
}

// ---------------- dwconv1 pass B: transpose (B,C,N) -> (B,N,C) ----------------
__global__ __launch_bounds__(256) void transpose_in(
    const float* __restrict__ in, float* __restrict__ out)
{
    __shared__ float t[32][33];
    int b = blockIdx.z;
    int n0 = blockIdx.y * 32;
    int c0 = blockIdx.x * 32;
    int tx = threadIdx.x, ty = threadIdx.y;   // 32 x 8
    for (int i = ty; i < 32; i += 8) {
        int n = n0 + tx;
        if (n < NTOK) t[i][tx] = in[((size_t)b * CDIM + c0 + i) * NTOK + n];
    }
    __syncthreads();
    for (int i = ty; i < 32; i += 8) {
        int n = n0 + i;
        if (n < NTOK) out[((size_t)b * NTOK + n) * CDIM + c0 + tx] = t[tx][i];
    }
}

// ---------------- dwconv2 in (B,N,C) layout, with residual ----------------
__global__ __launch_bounds__(256) void dwconv_bnc(
    const float* __restrict__ xin, const float* __restrict__ w,
    const float* __restrict__ bias, float* __restrict__ xout)
{
    size_t g = (size_t)blockIdx.x * 256 + threadIdx.x;
    if (g >= (size_t)BN * CDIM) return;
    int c = (int)(g % CDIM);
    size_t r = g / CDIM;
    int n = (int)(r % NTOK);
    int b = (int)(r / NTOK);
    int h = n / WW, wcol = n % WW;
    const float* wp = w + c * 9;
    const float* base = xin + (size_t)b * NTOK * CDIM;
    float s = 0.f;
#pragma unroll
    for (int di = -1; di <= 1; di++) {
#pragma unroll
        for (int dj = -1; dj <= 1; dj++) {
            int hh = h + di, ww2 = wcol + dj;
            if (hh >= 0 && hh < HH && ww2 >= 0 && ww2 < WW)
                s += wp[(di + 1) * 3 + (dj + 1)] * base[(size_t)(hh * WW + ww2) * CDIM + c];
        }
    }
    xout[g] = xin[g] + s + bias[c];
}

// ---------------- LayerNorm over C=384, one wave per token; TO = float or bf16 ----------
template <typename TO>
__global__ __launch_bounds__(256) void layernorm_k(
    const float* __restrict__ in, const float* __restrict__ g,
    const float* __restrict__ b, TO* __restrict__ out)
{
    int wid = threadIdx.x >> 6;
    int lane = threadIdx.x & 63;
    size_t r = (size_t)blockIdx.x * 4 + wid;
    const float* row = in + r * CDIM;
    float v[6];
    float s = 0.f;
#pragma unroll
    for (int j = 0; j < 6; j++) { v[j] = row[lane + 64 * j]; s += v[j]; }
#pragma unroll
    for (int off = 32; off >= 1; off >>= 1) s += __shfl_xor(s, off);
    float mu = s * (1.f / CDIM);
    float q = 0.f;
#pragma unroll
    for (int j = 0; j < 6; j++) { float d = v[j] - mu; q += d * d; }
#pragma unroll
    for (int off = 32; off >= 1; off >>= 1) q += __shfl_xor(q, off);
    float rs = rsqrtf(q * (1.f / CDIM) + LN_EPS);
    TO* orow = out + r * CDIM;
#pragma unroll
    for (int j = 0; j < 6; j++) {
        int c = lane + 64 * j;
        stf(&orow[c], (v[j] - mu) * rs * g[c] + b[c]);
    }
}

// ---------------- MFMA GEMM: Co = A(rows x K) * Bw(M x K)^T [+bias][+res][gelu] -------
template <int ACT, bool RES, typename TO>
__global__ __launch_bounds__(256) void gemm_mfma(
    const short* __restrict__ Abf, const short* __restrict__ Bw,
    const float* __restrict__ bias, const float* __restrict__ res,
    TO* __restrict__ Co, int K, int M)
{
    __shared__ short As[4096];   // 128 rows x 32 cols bf16, swizzled granules
    __shared__ short Bs[4096];
    const int tid = threadIdx.x;
    const int wid = tid >> 6, lane = tid & 63;
    const int wrow = wid >> 1, wcol = wid & 1;
    const int quad = lane >> 4, lr = lane & 15;
    const int r0 = blockIdx.y * 128, m0 = blockIdx.x * 128;

    const int inst0 = wid * 2;
    const int row0 = inst0 * 16 + (lane >> 2);
    const int row1 = row0 + 16;
    const int q0 = (lane & 3) ^ ((row0 >> 1) & 3);
    const int q1 = (lane & 3) ^ ((row1 >> 1) & 3);
    const short* gA0 = Abf + (size_t)(r0 + row0) * K + q0 * 8;
    const short* gA1 = Abf + (size_t)(r0 + row1) * K + q1 * 8;
    const short* gB0 = Bw + (size_t)(m0 + row0) * K + q0 * 8;
    const short* gB1 = Bw + (size_t)(m0 + row1) * K + q1 * 8;
    short* lA0 = As + inst0 * 512;
    short* lA1 = lA0 + 512;
    short* lB0 = Bs + inst0 * 512;
    short* lB1 = lB0 + 512;

    const short* fA[4];
    const short* fB[4];
#pragma unroll
    for (int i = 0; i < 4; i++) {
        int ar = wrow * 64 + i * 16 + lr;
        fA[i] = As + (ar * 4 + (quad ^ ((ar >> 1) & 3))) * 8;
        int br = wcol * 64 + i * 16 + lr;
        fB[i] = Bs + (br * 4 + (quad ^ ((br >> 1) & 3))) * 8;
    }

    f32x4 acc[4][4] = {};

    for (int k0 = 0; k0 < K; k0 += 32) {
        gload16(gA0, lA0); gload16(gA1, lA1);
        gload16(gB0, lB0); gload16(gB1, lB1);
        gA0 += 32; gA1 += 32; gB0 += 32; gB1 += 32;
        __syncthreads();
        bf16x8 av[4], bv[4];
#pragma unroll
        for (int i = 0; i < 4; i++) {
            av[i] = *(const bf16x8*)fA[i];
            bv[i] = *(const bf16x8*)fB[i];
        }
#pragma unroll
        for (int i = 0; i < 4; i++)
#pragma unroll
            for (int j = 0; j < 4; j++)
                acc[i][j] = __builtin_amdgcn_mfma_f32_16x16x32_bf16(
                    av[i], bv[j], acc[i][j], 0, 0, 0);
        __syncthreads();
    }

#pragma unroll
    for (int i = 0; i < 4; i++) {
        int gr = r0 + wrow * 64 + i * 16 + quad * 4;
#pragma unroll
        for (int j = 0; j < 4; j++) {
            int gc = m0 + wcol * 64 + j * 16 + lr;
            float bb = bias ? bias[gc] : 0.f;
#pragma unroll
            for (int rreg = 0; rreg < 4; rreg++) {
                size_t idx = (size_t)(gr + rreg) * M + gc;
                float v = acc[i][j][rreg] + bb;
                if (RES) v += res[idx];
                if (ACT == 1) v = 0.5f * v * (1.f + erff(v * 0.70710678118f));
                stf(&Co[idx], v);
            }
        }
    }
}

// ---------------- channel attention: attn[b,h,d,e] = softmax_e(SCALE * sum_n k*v) ------
__global__ __launch_bounds__(256) void attn_k(
    const bf16* __restrict__ qkv, float* __restrict__ attn)
{
    int bh = blockIdx.x;
    int b = bh / NHEADS, h = bh % NHEADS;
    __shared__ float ks[64][32];
    __shared__ float vs[64][32];
    __shared__ float sm[32][33];
    int tid = threadIdx.x;
    int d = tid >> 3, e0 = (tid & 7) * 4;
    float acc[4] = {0.f, 0.f, 0.f, 0.f};
    for (int n0 = 0; n0 < NTOK; n0 += 64) {
#pragma unroll
        for (int i = 0; i < 8; i++) {
            int idx = tid + i * 256;   // 0..2047
            int nn = idx >> 5, cc = idx & 31;
            int n = n0 + nn;
            float kv = 0.f, vv = 0.f;
            if (n < NTOK) {
                size_t base = ((size_t)b * NTOK + n) * (3 * CDIM);
                kv = ATT_SCALE * __bfloat162float(qkv[base + CDIM + h * HDIM + cc]);
                vv = __bfloat162float(qkv[base + 2 * CDIM + h * HDIM + cc]);
            }
            ks[nn][cc] = kv; vs[nn][cc] = vv;
        }
        __syncthreads();
#pragma unroll 8
        for (int nn = 0; nn < 64; nn++) {
            float kd = ks[nn][d];
#pragma unroll
            for (int j = 0; j < 4; j++) acc[j] += kd * vs[nn][e0 + j];
        }
        __syncthreads();
    }
#pragma unroll
    for (int j = 0; j < 4; j++) sm[d][e0 + j] = acc[j];
    __syncthreads();
    if (tid < 32) {
        float mx = -1e30f;
#pragma unroll
        for (int e = 0; e < 32; e++) mx = fmaxf(mx, sm[tid][e]);
        float ssum = 0.f;
        float ex[32];
#pragma unroll
        for (int e = 0; e < 32; e++) { ex[e] = expf(sm[tid][e] - mx); ssum += ex[e]; }
        float inv = 1.f / ssum;
        float* arow = attn + ((size_t)bh * 32 + tid) * 32;
#pragma unroll
        for (int e = 0; e < 32; e++) arow[e] = ex[e] * inv;
    }
}

// ---------------- apply attention: out[b,n,c=h*32+d] = sum_e attn[b,h,d,e]*q[b,n,h,e] --
__global__ __launch_bounds__(384) void apply_attn_k(
    const bf16* __restrict__ qkv, const float* __restrict__ attn,
    bf16* __restrict__ out)
{
    int b = blockIdx.x;
    int chunk = blockIdx.y;            // 8 chunks of 98 tokens
    __shared__ float at[NHEADS][32][33];
    __shared__ float qs[CDIM];
    int tid = threadIdx.x;             // 0..383
#pragma unroll
    for (int i = 0; i < 32; i++) {
        int idx = tid + i * 384;       // 0..12287
        int hh = idx >> 10, dd = (idx >> 5) & 31, ee = idx & 31;
        at[hh][dd][ee] = attn[((size_t)(b * NHEADS + hh) * 32 + dd) * 32 + ee];
    }
    int h = tid >> 5, d = tid & 31;
    for (int t = 0; t < 98; t++) {
        int n = chunk * 98 + t;
        size_t base = ((size_t)b * NTOK + n) * (3 * CDIM);
        __syncthreads();
        qs[tid] = __bfloat162float(qkv[base + tid]);   // q slice
        __syncthreads();
        float s = 0.f;
#pragma unroll
        for (int e = 0; e < 32; e++) s += at[h][d][e] * qs[h * 32 + e];
        out[((size_t)b * NTOK + n) * CDIM + tid] = __float2bfloat16(s);
    }
}

// ---------------- final transpose: (B,N,C) -> (B,C,H,W) ----------------
__global__ __launch_bounds__(256) void transpose_out(
    const float* __restrict__ in, float* __restrict__ out)
{
    __shared__ float t[32][33];
    int b = blockIdx.z;
    int n0 = blockIdx.y * 32;
    int c0 = blockIdx.x * 32;
    int tx = threadIdx.x, ty = threadIdx.y;   // 32 x 8
    for (int i = ty; i < 32; i += 8) {
        int n = n0 + i;
        if (n < NTOK) t[i][tx] = in[((size_t)b * NTOK + n) * CDIM + c0 + tx];
    }
    __syncthreads();
    for (int i = ty; i < 32; i += 8) {
        int c = c0 + i;
        int n = n0 + tx;
        if (n < NTOK) out[((size_t)b * CDIM + c) * NTOK + n] = t[tx][i];
    }
}

extern "C" void kernel_launch(void* const* d_in, const int* in_sizes, int n_in,
                              void* d_out, int out_size, void* d_ws, size_t ws_size,
                              hipStream_t stream) {
    const float* x      = (const float*)d_in[0];
    const float* cpe1_w = (const float*)d_in[1];
    const float* cpe1_b = (const float*)d_in[2];
    const float* n1g    = (const float*)d_in[3];
    const float* n1b    = (const float*)d_in[4];
    const float* qkv_w  = (const float*)d_in[5];
    const float* proj_w = (const float*)d_in[6];
    const float* proj_b = (const float*)d_in[7];
    const float* cpe2_w = (const float*)d_in[8];
    const float* cpe2_b = (const float*)d_in[9];
    const float* n2g    = (const float*)d_in[10];
    const float* n2b    = (const float*)d_in[11];
    const float* fc1_w  = (const float*)d_in[12];
    const float* fc1_b  = (const float*)d_in[13];
    const float* fc2_w  = (const float*)d_in[14];
    const float* fc2_b  = (const float*)d_in[15];

    const size_t A = (size_t)BN * CDIM;        // 9,633,792
    const size_t HA = A / 2;

    // bf16 weights live at the front of ws (1,769,472 shorts = 884,736 floats)
    bf16* wqkv  = (bf16*)d_ws;                 // 1152*384 = 442368
    bf16* wproj = wqkv + 442368;               // 384*384  = 147456
    bf16* wfc1  = wproj + 147456;              // 1536*384 = 589824
    bf16* wfc2  = wfc1 + 589824;               // 384*1536 = 589824
    float* base = (float*)d_ws + 884736;

    float* xt        = base;                   // [0, A)        residual stream
    bf16*  curb      = (bf16*)(base + A);      // [A, 1.5A)     LN1 out (bf16)
    bf16*  ylnb      = (bf16*)(base + A);      // phase-2 reuse LN2 out (bf16)
    bf16*  qkvb      = (bf16*)(base + A + HA); // [1.5A, 3A)    qkv (bf16, 3A elems)
    float* x3        = base + A + HA;          // phase-2 reuse [1.5A, 2.5A)
    bf16*  h1        = (bf16*)(base + A + HA + A); // [2.5A, 4.5A) fc1 out (bf16, 4A elems)
    float* attnm     = base + 3 * A;           // [3A, +393216)
    bf16*  attn_outb = (bf16*)(base + 3 * A + 393216); // 0.5A floats
    float* finalb    = base;                   // xt region reuse
    float* xconv     = base + (A * 7) / 2;     // [3.5A, 4.5A)  dwconv1 NCHW temp (dead after 1b)
    // peak = 884736 + 4.5A floats = 176.9 MB

    // 0. weight conversion fp32 -> bf16
    f2b_k<<<(442368 + 255) / 256, 256, 0, stream>>>(qkv_w, wqkv, 442368);
    f2b_k<<<(147456 + 255) / 256, 256, 0, stream>>>(proj_w, wproj, 147456);
    f2b_k<<<(589824 + 255) / 256, 256, 0, stream>>>(fc1_w, wfc1, 589824);
    f2b_k<<<(589824 + 255) / 256, 256, 0, stream>>>(fc2_w, wfc2, 589824);

    // 1a. cpe1 + residual in NCHW (coalesced, LDS-planed)
    dwconv_nchw_plane<<<BBATCH * CDIM, 256, 0, stream>>>(x, cpe1_w, cpe1_b, xconv);
    // 1b. transpose (B,C,N) -> (B,N,C)
    transpose_in<<<dim3(CDIM / 32, (NTOK + 31) / 32, BBATCH), dim3(32, 8), 0, stream>>>(
        xconv, xt);
    // 2. LN1 -> bf16
    layernorm_k<bf16><<<BN / 4, 256, 0, stream>>>(xt, n1g, n1b, curb);
    // 3. qkv GEMM (bf16 MFMA, out bf16)
    gemm_mfma<0, false, bf16><<<dim3(1152 / 128, BN / 128), 256, 0, stream>>>(
        (const short*)curb, (const short*)wqkv, nullptr, nullptr, qkvb, 384, 1152);
    // 4. channel attention matrices + softmax
    attn_k<<<BBATCH * NHEADS, 256, 0, stream>>>(qkvb, attnm);
    // 5. apply attention to q (out bf16)
    apply_attn_k<<<dim3(BBATCH, 8), 384, 0, stream>>>(qkvb, attnm, attn_outb);
    // 6. proj GEMM + bias + residual (in-place into xt)
    gemm_mfma<0, true, float><<<dim3(384 / 128, BN / 128), 256, 0, stream>>>(
        (const short*)attn_outb, (const short*)wproj, proj_b, xt, xt, 384, 384);
    // 7. cpe2 + residual in (B,N,C)
    dwconv_bnc<<<(int)((A + 255) / 256), 256, 0, stream>>>(xt, cpe2_w, cpe2_b, x3);
    // 8. LN2 -> bf16
    layernorm_k<bf16><<<BN / 4, 256, 0, stream>>>(x3, n2g, n2b, ylnb);
    // 9. fc1 + bias + exact GELU (out bf16)
    gemm_mfma<1, false, bf16><<<dim3(1536 / 128, BN / 128), 256, 0, stream>>>(
        (const short*)ylnb, (const short*)wfc1, fc1_b, nullptr, h1, 384, 1536);
    // 10. fc2 + bias + residual(x3)
    gemm_mfma<0, true, float><<<dim3(384 / 128, BN / 128), 256, 0, stream>>>(
        (const short*)h1, (const short*)wfc2, fc2_b, x3, finalb, 1536, 384);
    // 11. (B,N,C) -> (B,C,H,W)
    transpose_out<<<dim3(CDIM / 32, (NTOK + 31) / 32, BBATCH), dim3(32, 8), 0, stream>>>(
        finalb, (float*)d_out);
}

// Round 4
// 549.233 us; speedup vs baseline: 4.4716x; 1.0847x over previous
//
#include <hip/hip_runtime.h>
#include <hip/hip_bf16.h>

#define CDIM 384
#define NHEADS 12
#define HDIM 32
#define HIDDEN 1536
#define BBATCH 32
#define HH 28
#define WW 28
#define NTOK 784
#define BN (BBATCH * NTOK)   // 25088
#define LN_EPS 1e-5f
#define ATT_SCALE 0.17677669529663687f

typedef __hip_bfloat16 bf16;
typedef __attribute__((ext_vector_type(8))) short bf16x8;
typedef __attribute__((ext_vector_type(4))) float f32x4;

__device__ __forceinline__ float ldf(const float* p) { return *p; }
__device__ __forceinline__ float ldf(const bf16* p) { return __bfloat162float(*p); }
__device__ __forceinline__ void stf(float* p, float v) { *p = v; }
__device__ __forceinline__ void stf(bf16* p, float v) { *p = __float2bfloat16(v); }

__device__ __forceinline__ short f2bs(float v) {
    bf16 t = __float2bfloat16(v);
    return *reinterpret_cast<short*>(&t);
}

// tanh-form GELU as sigmoid: x * sigmoid(2*sqrt(2/pi)*(x + 0.044715 x^3))
// max |diff| vs exact erf-GELU ~3e-4, far inside tolerance. ~10 VALU ops vs erff's ~30+.
__device__ __forceinline__ float gelu_f(float x) {
    float u = x * (0.7978845608f + 0.0356774081f * x * x);  // sqrt(2/pi)*(x+0.044715x^3)
    float e = __expf(-2.f * u);
    return x / (1.f + e);
}

__device__ __forceinline__ void gload16(const void* g, void* l) {
    __builtin_amdgcn_global_load_lds(
        (const __attribute__((address_space(1))) unsigned int*)g,
        (__attribute__((address_space(3))) unsigned int*)l, 16, 0, 0);
}

// ---------------- fp32 -> bf16 weight conversion (all 4 weights, one launch) ------------
__global__ __launch_bounds__(256) void f2b4_k(
    const float* __restrict__ w0, const float* __restrict__ w1,
    const float* __restrict__ w2, const float* __restrict__ w3,
    bf16* __restrict__ dst)
{
    int i = blockIdx.x * 256 + threadIdx.x;   // 0..1769471, dst regions contiguous
    const float* src; int off;
    if (i < 442368)       { src = w0; off = i; }
    else if (i < 589824)  { src = w1; off = i - 442368; }
    else if (i < 1179648) { src = w2; off = i - 589824; }
    else                  { src = w3; off = i - 1179648; }
    dst[i] = __float2bfloat16(src[off]);
}

// ---------------- dwconv1 pass A: per-(b,c) plane conv in NCHW, coalesced ----------------
__global__ __launch_bounds__(256) void dwconv_nchw_plane(
    const float* __restrict__ x, const float* __restrict__ w,
    const float* __restrict__ bias, float* __restrict__ y)
{
    __shared__ float sm[NTOK];
    int bc = blockIdx.x;                    // b*CDIM + c
    int c = bc % CDIM;
    const float* xp = x + (size_t)bc * NTOK;
    int tid = threadIdx.x;
#pragma unroll
    for (int i = 0; i < 4; i++) {
        int p = tid + i * 256;
        if (p < NTOK) sm[p] = xp[p];
    }
    __syncthreads();
    const float* wp = w + c * 9;
    float w00 = wp[0], w01 = wp[1], w02 = wp[2];
    float w10 = wp[3], w11 = wp[4], w12 = wp[5];
    float w20 = wp[6], w21 = wp[7], w22 = wp[8];
    float bc_ = bias[c];
    float* yp = y + (size_t)bc * NTOK;
#pragma unroll
    for (int i = 0; i < 4; i++) {
        int p = tid + i * 256;
        if (p >= NTOK) break;
        int h = p / WW, wcol = p % WW;
        bool hm = h > 0, hp = h < HH - 1, wm = wcol > 0, wpv = wcol < WW - 1;
        float s = w11 * sm[p];
        if (hm)        s += w01 * sm[p - WW];
        if (hp)        s += w21 * sm[p + WW];
        if (wm)        s += w10 * sm[p - 1];
        if (wpv)       s += w12 * sm[p + 1];
        if (hm && wm)  s += w00 * sm[p - WW - 1];
        if (hm && wpv) s += w02 * sm[p - WW + 1];
        if (hp && wm)  s += w20 * sm[p + WW - 1];
        if (hp && wpv) s += w22 * sm[p + WW + 1];
        yp[p] = sm[p] + s + bc_;
    }
}

// ---------------- dwconv1 pass B: transpose (B,C,N) -> (B,N,C) ----------------
__global__ __launch_bounds__(256) void transpose_in(
    const float* __restrict__ in, float* __restrict__ out)
{
    __shared__ float t[32][33];
    int b = blockIdx.z;
    int n0 = blockIdx.y * 32;
    int c0 = blockIdx.x * 32;
    int tx = threadIdx.x, ty = threadIdx.y;   // 32 x 8
    for (int i = ty; i < 32; i += 8) {
        int n = n0 + tx;
        if (n < NTOK) t[i][tx] = in[((size_t)b * CDIM + c0 + i) * NTOK + n];
    }
    __syncthreads();
    for (int i = ty; i < 32; i += 8) {
        int n = n0 + i;
        if (n < NTOK) out[((size_t)b * NTOK + n) * CDIM + c0 + tx] = t[tx][i];
    }
}

// ---------------- dwconv2 in (B,N,C) layout, with residual ----------------
__global__ __launch_bounds__(256) void dwconv_bnc(
    const float* __restrict__ xin, const float* __restrict__ w,
    const float* __restrict__ bias, float* __restrict__ xout)
{
    size_t g = (size_t)blockIdx.x * 256 + threadIdx.x;
    if (g >= (size_t)BN * CDIM) return;
    int c = (int)(g % CDIM);
    size_t r = g / CDIM;
    int n = (int)(r % NTOK);
    int b = (int)(r / NTOK);
    int h = n / WW, wcol = n % WW;
    const float* wp = w + c * 9;
    const float* base = xin + (size_t)b * NTOK * CDIM;
    float s = 0.f;
#pragma unroll
    for (int di = -1; di <= 1; di++) {
#pragma unroll
        for (int dj = -1; dj <= 1; dj++) {
            int hh = h + di, ww2 = wcol + dj;
            if (hh >= 0 && hh < HH && ww2 >= 0 && ww2 < WW)
                s += wp[(di + 1) * 3 + (dj + 1)] * base[(size_t)(hh * WW + ww2) * CDIM + c];
        }
    }
    xout[g] = xin[g] + s + bias[c];
}

// ---------------- LayerNorm over C=384, one wave per token; TO = float or bf16 ----------
template <typename TO>
__global__ __launch_bounds__(256) void layernorm_k(
    const float* __restrict__ in, const float* __restrict__ g,
    const float* __restrict__ b, TO* __restrict__ out)
{
    int wid = threadIdx.x >> 6;
    int lane = threadIdx.x & 63;
    size_t r = (size_t)blockIdx.x * 4 + wid;
    const float* row = in + r * CDIM;
    float v[6];
    float s = 0.f;
#pragma unroll
    for (int j = 0; j < 6; j++) { v[j] = row[lane + 64 * j]; s += v[j]; }
#pragma unroll
    for (int off = 32; off >= 1; off >>= 1) s += __shfl_xor(s, off);
    float mu = s * (1.f / CDIM);
    float q = 0.f;
#pragma unroll
    for (int j = 0; j < 6; j++) { float d = v[j] - mu; q += d * d; }
#pragma unroll
    for (int off = 32; off >= 1; off >>= 1) q += __shfl_xor(q, off);
    float rs = rsqrtf(q * (1.f / CDIM) + LN_EPS);
    TO* orow = out + r * CDIM;
#pragma unroll
    for (int j = 0; j < 6; j++) {
        int c = lane + 64 * j;
        stf(&orow[c], (v[j] - mu) * rs * g[c] + b[c]);
    }
}

// ---------------- MFMA GEMM v2: Co = A(rows x K) * Bw(M x K)^T [+bias][+res][gelu] -----
// 128x128 tile, 4 waves, BK=64, 16x16x32 bf16 MFMA (32 MFMA/wave per barrier pair).
// LDS granule swizzle: slot(row, g) = g ^ (row & 7); conflict-free for both the
// wave-uniform global_load_lds staging (lane L -> row L>>3, slot L&7) and the
// ds_read_b128 fragment reads (balanced 8 accesses/bank = structural min).
// bf16 output goes through an LDS-staged epilogue (full-line coalesced stores; kills
// the write-allocate HBM fetch seen in v1). fp32 output stores directly (already
// full 64B lines).
template <int ACT, bool RES, typename TO>
__global__ __launch_bounds__(256) void gemm_mfma(
    const short* __restrict__ Abf, const short* __restrict__ Bw,
    const float* __restrict__ bias, const float* __restrict__ res,
    TO* __restrict__ Co, int K, int M)
{
    __shared__ short lds[16896];          // 33 KB: staging As|Bs (16K shorts), epilogue Cs
    short* As = lds;
    short* Bs = lds + 8192;
    const int tid = threadIdx.x;
    const int wid = tid >> 6, lane = tid & 63;
    const int wrow = wid >> 1, wcol = wid & 1;
    const int quad = lane >> 4, lr = lane & 15;
    const int r0 = blockIdx.y * 128, m0 = blockIdx.x * 128;

    // staging: 16 insts/matrix (8 rows x 8 granules each); wave w issues insts 4w..4w+3
    const int srow = lane >> 3;            // row within 8-row group
    const int sg   = (lane & 7) ^ srow;    // granule fetched so LDS slot (lane&7) holds it
    const short* gA = Abf + (size_t)(r0 + wid * 32 + srow) * K + sg * 8;
    const short* gB = Bw  + (size_t)(m0 + wid * 32 + srow) * K + sg * 8;
    short* lA = As + wid * 2048;
    short* lB = Bs + wid * 2048;

    // fragment offsets: row ar -> ar*64 shorts; granule (s*4+quad) at slot ^(ar&7)
    int fAoff[4], fBoff[4];
#pragma unroll
    for (int i = 0; i < 4; i++) {
        fAoff[i] = (wrow * 64 + i * 16 + lr) * 64;
        fBoff[i] = (wcol * 64 + i * 16 + lr) * 64;
    }
    const int slot0 = ((0 + quad) ^ (lr & 7)) * 8;
    const int slot1 = ((4 + quad) ^ (lr & 7)) * 8;

    f32x4 acc[4][4] = {};

    for (int k0 = 0; k0 < K; k0 += 64) {
#pragma unroll
        for (int k = 0; k < 4; k++) {
            gload16(gA + k0 + (size_t)k * 8 * K, lA + k * 512);
            gload16(gB + k0 + (size_t)k * 8 * K, lB + k * 512);
        }
        __syncthreads();
#pragma unroll
        for (int s = 0; s < 2; s++) {
            const int so = s ? slot1 : slot0;
            bf16x8 av[4], bv[4];
#pragma unroll
            for (int i = 0; i < 4; i++) {
                av[i] = *(const bf16x8*)(As + fAoff[i] + so);
                bv[i] = *(const bf16x8*)(Bs + fBoff[i] + so);
            }
#pragma unroll
            for (int i = 0; i < 4; i++)
#pragma unroll
                for (int j = 0; j < 4; j++)
                    acc[i][j] = __builtin_amdgcn_mfma_f32_16x16x32_bf16(
                        av[i], bv[j], acc[i][j], 0, 0, 0);
        }
        __syncthreads();
    }

    if constexpr (sizeof(TO) == 4) {
        // fp32: direct stores (16 lanes x 4B = full 64B lines)
#pragma unroll
        for (int i = 0; i < 4; i++) {
            int gr = r0 + wrow * 64 + i * 16 + quad * 4;
#pragma unroll
            for (int j = 0; j < 4; j++) {
                int gc = m0 + wcol * 64 + j * 16 + lr;
                float bb = bias ? bias[gc] : 0.f;
#pragma unroll
                for (int rr = 0; rr < 4; rr++) {
                    size_t idx = (size_t)(gr + rr) * M + gc;
                    float v = acc[i][j][rr] + bb;
                    if (RES) v += res[idx];
                    if (ACT == 1) v = gelu_f(v);
                    stf((float*)&Co[idx], v);
                }
            }
        }
    } else {
        // bf16: stage tile in LDS (stride 132 shorts -> 2-way-free b16 writes),
        // then coalesced full-line readback stores.
        short* Cs = lds;                   // reuse; K-loop's trailing barrier protects
#pragma unroll
        for (int i = 0; i < 4; i++) {
            int lrow = wrow * 64 + i * 16 + quad * 4;
#pragma unroll
            for (int j = 0; j < 4; j++) {
                int lcol = wcol * 64 + j * 16 + lr;
                float bb = bias ? bias[m0 + lcol] : 0.f;
#pragma unroll
                for (int rr = 0; rr < 4; rr++) {
                    float v = acc[i][j][rr] + bb;
                    if (ACT == 1) v = gelu_f(v);
                    Cs[(lrow + rr) * 132 + lcol] = f2bs(v);
                }
            }
        }
        __syncthreads();
        short* co = (short*)Co;
#pragma unroll
        for (int s = 0; s < 16; s++) {
            int row = s * 8 + (tid >> 5);
            int seg = tid & 31;
            uint2 vv = *(const uint2*)(Cs + row * 132 + seg * 4);
            *(uint2*)(co + (size_t)(r0 + row) * M + m0 + seg * 4) = vv;
        }
    }
}

// ---------------- channel attention: attn[b,h,d,e] = softmax_e(SCALE * sum_n k*v) ------
__global__ __launch_bounds__(256) void attn_k(
    const bf16* __restrict__ qkv, float* __restrict__ attn)
{
    int bh = blockIdx.x;
    int b = bh / NHEADS, h = bh % NHEADS;
    __shared__ float ks[64][32];
    __shared__ float vs[64][32];
    __shared__ float sm[32][33];
    int tid = threadIdx.x;
    int d = tid >> 3, e0 = (tid & 7) * 4;
    float acc[4] = {0.f, 0.f, 0.f, 0.f};
    for (int n0 = 0; n0 < NTOK; n0 += 64) {
#pragma unroll
        for (int i = 0; i < 8; i++) {
            int idx = tid + i * 256;   // 0..2047
            int nn = idx >> 5, cc = idx & 31;
            int n = n0 + nn;
            float kv = 0.f, vv = 0.f;
            if (n < NTOK) {
                size_t base = ((size_t)b * NTOK + n) * (3 * CDIM);
                kv = ATT_SCALE * __bfloat162float(qkv[base + CDIM + h * HDIM + cc]);
                vv = __bfloat162float(qkv[base + 2 * CDIM + h * HDIM + cc]);
            }
            ks[nn][cc] = kv; vs[nn][cc] = vv;
        }
        __syncthreads();
#pragma unroll 8
        for (int nn = 0; nn < 64; nn++) {
            float kd = ks[nn][d];
#pragma unroll
            for (int j = 0; j < 4; j++) acc[j] += kd * vs[nn][e0 + j];
        }
        __syncthreads();
    }
#pragma unroll
    for (int j = 0; j < 4; j++) sm[d][e0 + j] = acc[j];
    __syncthreads();
    if (tid < 32) {
        float mx = -1e30f;
#pragma unroll
        for (int e = 0; e < 32; e++) mx = fmaxf(mx, sm[tid][e]);
        float ssum = 0.f;
        float ex[32];
#pragma unroll
        for (int e = 0; e < 32; e++) { ex[e] = expf(sm[tid][e] - mx); ssum += ex[e]; }
        float inv = 1.f / ssum;
        float* arow = attn + ((size_t)bh * 32 + tid) * 32;
#pragma unroll
        for (int e = 0; e < 32; e++) arow[e] = ex[e] * inv;
    }
}

// ---------------- apply attention v2: attn row in registers, 8-token staged chunks -----
// out[b,n,c=h*32+d] = sum_e attn[b,h,d,e] * q[b,n,h*32+e]
__global__ __launch_bounds__(384) void apply_attn_k(
    const bf16* __restrict__ qkv, const float* __restrict__ attn,
    bf16* __restrict__ out)
{
    int b = blockIdx.x;
    int chunk = blockIdx.y;            // 14 chunks of 56 tokens
    int tid = threadIdx.x;             // 0..383
    int h = tid >> 5;
    __shared__ float qs[8][CDIM];
    // this thread's attn row (32 floats) in registers, vectorized load
    float at[32];
    const float4* ap = (const float4*)(attn + ((size_t)(b * NHEADS) * 32 + tid) * 32);
#pragma unroll
    for (int e4 = 0; e4 < 8; e4++) {
        float4 v = ap[e4];
        at[e4 * 4 + 0] = v.x; at[e4 * 4 + 1] = v.y;
        at[e4 * 4 + 2] = v.z; at[e4 * 4 + 3] = v.w;
    }
    int nbase = chunk * 56;
    for (int t0 = 0; t0 < 56; t0 += 8) {
        __syncthreads();
#pragma unroll
        for (int i = 0; i < 8; i++) {
            int n = nbase + t0 + i;
            qs[i][tid] = __bfloat162float(qkv[((size_t)b * NTOK + n) * (3 * CDIM) + tid]);
        }
        __syncthreads();
#pragma unroll
        for (int i = 0; i < 8; i++) {
            const float* qrow = &qs[i][h * 32];
            float s = 0.f;
#pragma unroll
            for (int e = 0; e < 32; e++) s += at[e] * qrow[e];
            int n = nbase + t0 + i;
            out[((size_t)b * NTOK + n) * CDIM + tid] = __float2bfloat16(s);
        }
    }
}

// ---------------- final transpose: (B,N,C) -> (B,C,H,W) ----------------
__global__ __launch_bounds__(256) void transpose_out(
    const float* __restrict__ in, float* __restrict__ out)
{
    __shared__ float t[32][33];
    int b = blockIdx.z;
    int n0 = blockIdx.y * 32;
    int c0 = blockIdx.x * 32;
    int tx = threadIdx.x, ty = threadIdx.y;   // 32 x 8
    for (int i = ty; i < 32; i += 8) {
        int n = n0 + i;
        if (n < NTOK) t[i][tx] = in[((size_t)b * NTOK + n) * CDIM + c0 + tx];
    }
    __syncthreads();
    for (int i = ty; i < 32; i += 8) {
        int c = c0 + i;
        int n = n0 + tx;
        if (n < NTOK) out[((size_t)b * CDIM + c) * NTOK + n] = t[tx][i];
    }
}

extern "C" void kernel_launch(void* const* d_in, const int* in_sizes, int n_in,
                              void* d_out, int out_size, void* d_ws, size_t ws_size,
                              hipStream_t stream) {
    const float* x      = (const float*)d_in[0];
    const float* cpe1_w = (const float*)d_in[1];
    const float* cpe1_b = (const float*)d_in[2];
    const float* n1g    = (const float*)d_in[3];
    const float* n1b    = (const float*)d_in[4];
    const float* qkv_w  = (const float*)d_in[5];
    const float* proj_w = (const float*)d_in[6];
    const float* proj_b = (const float*)d_in[7];
    const float* cpe2_w = (const float*)d_in[8];
    const float* cpe2_b = (const float*)d_in[9];
    const float* n2g    = (const float*)d_in[10];
    const float* n2b    = (const float*)d_in[11];
    const float* fc1_w  = (const float*)d_in[12];
    const float* fc1_b  = (const float*)d_in[13];
    const float* fc2_w  = (const float*)d_in[14];
    const float* fc2_b  = (const float*)d_in[15];

    const size_t A = (size_t)BN * CDIM;        // 9,633,792
    const size_t HA = A / 2;

    // bf16 weights contiguous at front of ws
    bf16* wqkv  = (bf16*)d_ws;                 // 442368
    bf16* wproj = wqkv + 442368;               // 147456
    bf16* wfc1  = wproj + 147456;              // 589824
    bf16* wfc2  = wfc1 + 589824;               // 589824
    float* base = (float*)d_ws + 884736;

    float* xt        = base;                   // [0, A)        residual stream
    bf16*  curb      = (bf16*)(base + A);      // [A, 1.5A)     LN1 out (bf16)
    bf16*  ylnb      = (bf16*)(base + A);      // phase-2 reuse LN2 out (bf16)
    bf16*  qkvb      = (bf16*)(base + A + HA); // [1.5A, 3A)    qkv (bf16, 3A elems)
    float* x3        = base + A + HA;          // phase-2 reuse [1.5A, 2.5A)
    bf16*  h1        = (bf16*)(base + A + HA + A); // [2.5A, 4.5A) fc1 out (bf16, 4A elems)
    float* attnm     = base + 3 * A;           // [3A, +393216)
    bf16*  attn_outb = (bf16*)(base + 3 * A + 393216);
    float* finalb    = base;                   // xt region reuse
    float* xconv     = base + (A * 7) / 2;     // [3.5A, 4.5A)  dwconv1 NCHW temp

    // 0. weight conversion fp32 -> bf16 (single launch; dst regions contiguous)
    f2b4_k<<<1769472 / 256, 256, 0, stream>>>(qkv_w, proj_w, fc1_w, fc2_w, wqkv);

    // 1a. cpe1 + residual in NCHW (coalesced, LDS-planed)
    dwconv_nchw_plane<<<BBATCH * CDIM, 256, 0, stream>>>(x, cpe1_w, cpe1_b, xconv);
    // 1b. transpose (B,C,N) -> (B,N,C)
    transpose_in<<<dim3(CDIM / 32, (NTOK + 31) / 32, BBATCH), dim3(32, 8), 0, stream>>>(
        xconv, xt);
    // 2. LN1 -> bf16
    layernorm_k<bf16><<<BN / 4, 256, 0, stream>>>(xt, n1g, n1b, curb);
    // 3. qkv GEMM (bf16 MFMA, out bf16)
    gemm_mfma<0, false, bf16><<<dim3(1152 / 128, BN / 128), 256, 0, stream>>>(
        (const short*)curb, (const short*)wqkv, nullptr, nullptr, qkvb, 384, 1152);
    // 4. channel attention matrices + softmax
    attn_k<<<BBATCH * NHEADS, 256, 0, stream>>>(qkvb, attnm);
    // 5. apply attention to q (out bf16)
    apply_attn_k<<<dim3(BBATCH, 14), 384, 0, stream>>>(qkvb, attnm, attn_outb);
    // 6. proj GEMM + bias + residual (in-place into xt)
    gemm_mfma<0, true, float><<<dim3(384 / 128, BN / 128), 256, 0, stream>>>(
        (const short*)attn_outb, (const short*)wproj, proj_b, xt, xt, 384, 384);
    // 7. cpe2 + residual in (B,N,C)
    dwconv_bnc<<<(int)((A + 255) / 256), 256, 0, stream>>>(xt, cpe2_w, cpe2_b, x3);
    // 8. LN2 -> bf16
    layernorm_k<bf16><<<BN / 4, 256, 0, stream>>>(x3, n2g, n2b, ylnb);
    // 9. fc1 + bias + GELU (out bf16)
    gemm_mfma<1, false, bf16><<<dim3(1536 / 128, BN / 128), 256, 0, stream>>>(
        (const short*)ylnb, (const short*)wfc1, fc1_b, nullptr, h1, 384, 1536);
    // 10. fc2 + bias + residual(x3)
    gemm_mfma<0, true, float><<<dim3(384 / 128, BN / 128), 256, 0, stream>>>(
        (const short*)h1, (const short*)wfc2, fc2_b, x3, finalb, 1536, 384);
    // 11. (B,N,C) -> (B,C,H,W)
    transpose_out<<<dim3(CDIM / 32, (NTOK + 31) / 32, BBATCH), dim3(32, 8), 0, stream>>>(
        finalb, (float*)d_out);
}

// Round 5
// 498.990 us; speedup vs baseline: 4.9219x; 1.1007x over previous
//
#include <hip/hip_runtime.h>
#include <hip/hip_bf16.h>

#define CDIM 384
#define NHEADS 12
#define HDIM 32
#define HIDDEN 1536
#define BBATCH 32
#define HH 28
#define WW 28
#define NTOK 784
#define BN (BBATCH * NTOK)   // 25088
#define LN_EPS 1e-5f
#define ATT_SCALE 0.17677669529663687f

typedef __hip_bfloat16 bf16;
typedef __attribute__((ext_vector_type(8))) short bf16x8;
typedef __attribute__((ext_vector_type(4))) float f32x4;

__device__ __forceinline__ float ldf(const float* p) { return *p; }
__device__ __forceinline__ float ldf(const bf16* p) { return __bfloat162float(*p); }
__device__ __forceinline__ void stf(float* p, float v) { *p = v; }
__device__ __forceinline__ void stf(bf16* p, float v) { *p = __float2bfloat16(v); }

__device__ __forceinline__ short f2bs(float v) {
    bf16 t = __float2bfloat16(v);
    return *reinterpret_cast<short*>(&t);
}

// tanh-form GELU via sigmoid; max |diff| vs exact ~3e-4, well inside tolerance.
__device__ __forceinline__ float gelu_f(float x) {
    float u = x * (0.7978845608f + 0.0356774081f * x * x);
    float e = __expf(-2.f * u);
    return x / (1.f + e);
}

__device__ __forceinline__ void gload16(const void* g, void* l) {
    __builtin_amdgcn_global_load_lds(
        (const __attribute__((address_space(1))) unsigned int*)g,
        (__attribute__((address_space(3))) unsigned int*)l, 16, 0, 0);
}

__device__ __forceinline__ void fma4(float4& a, float w, const float4& v) {
    a.x = fmaf(w, v.x, a.x); a.y = fmaf(w, v.y, a.y);
    a.z = fmaf(w, v.z, a.z); a.w = fmaf(w, v.w, a.w);
}

// ---------------- fp32 -> bf16 weight conversion (all 4 weights, one launch) ------------
__global__ __launch_bounds__(256) void f2b4_k(
    const float* __restrict__ w0, const float* __restrict__ w1,
    const float* __restrict__ w2, const float* __restrict__ w3,
    bf16* __restrict__ dst)
{
    int i = blockIdx.x * 256 + threadIdx.x;   // 0..1769471, dst regions contiguous
    const float* src; int off;
    if (i < 442368)       { src = w0; off = i; }
    else if (i < 589824)  { src = w1; off = i - 442368; }
    else if (i < 1179648) { src = w2; off = i - 589824; }
    else                  { src = w3; off = i - 1179648; }
    dst[i] = __float2bfloat16(src[off]);
}

// ---------------- transpose cpe2 weights (C,9) -> (9,C) ----------------
__global__ __launch_bounds__(256) void wtr_k(const float* __restrict__ w,
                                             float* __restrict__ wt)
{
    int i = blockIdx.x * 256 + threadIdx.x;   // 0..3455
    if (i < 9 * CDIM) {
        int k = i / CDIM, c = i % CDIM;
        wt[i] = w[c * 9 + k];
    }
}

// ---------------- dwconv1 pass A: per-(b,c) plane conv in NCHW, coalesced ----------------
__global__ __launch_bounds__(256) void dwconv_nchw_plane(
    const float* __restrict__ x, const float* __restrict__ w,
    const float* __restrict__ bias, float* __restrict__ y)
{
    __shared__ float sm[NTOK];
    int bc = blockIdx.x;                    // b*CDIM + c
    int c = bc % CDIM;
    const float* xp = x + (size_t)bc * NTOK;
    int tid = threadIdx.x;
#pragma unroll
    for (int i = 0; i < 4; i++) {
        int p = tid + i * 256;
        if (p < NTOK) sm[p] = xp[p];
    }
    __syncthreads();
    const float* wp = w + c * 9;
    float w00 = wp[0], w01 = wp[1], w02 = wp[2];
    float w10 = wp[3], w11 = wp[4], w12 = wp[5];
    float w20 = wp[6], w21 = wp[7], w22 = wp[8];
    float bc_ = bias[c];
    float* yp = y + (size_t)bc * NTOK;
#pragma unroll
    for (int i = 0; i < 4; i++) {
        int p = tid + i * 256;
        if (p >= NTOK) break;
        int h = p / WW, wcol = p % WW;
        bool hm = h > 0, hp = h < HH - 1, wm = wcol > 0, wpv = wcol < WW - 1;
        float s = w11 * sm[p];
        if (hm)        s += w01 * sm[p - WW];
        if (hp)        s += w21 * sm[p + WW];
        if (wm)        s += w10 * sm[p - 1];
        if (wpv)       s += w12 * sm[p + 1];
        if (hm && wm)  s += w00 * sm[p - WW - 1];
        if (hm && wpv) s += w02 * sm[p - WW + 1];
        if (hp && wm)  s += w20 * sm[p + WW - 1];
        if (hp && wpv) s += w22 * sm[p + WW + 1];
        yp[p] = sm[p] + s + bc_;
    }
}

// ---------------- dwconv1 pass B: transpose (B,C,N) -> (B,N,C) ----------------
__global__ __launch_bounds__(256) void transpose_in(
    const float* __restrict__ in, float* __restrict__ out)
{
    __shared__ float t[32][33];
    int b = blockIdx.z;
    int n0 = blockIdx.y * 32;
    int c0 = blockIdx.x * 32;
    int tx = threadIdx.x, ty = threadIdx.y;   // 32 x 8
    for (int i = ty; i < 32; i += 8) {
        int n = n0 + tx;
        if (n < NTOK) t[i][tx] = in[((size_t)b * CDIM + c0 + i) * NTOK + n];
    }
    __syncthreads();
    for (int i = ty; i < 32; i += 8) {
        int n = n0 + i;
        if (n < NTOK) out[((size_t)b * NTOK + n) * CDIM + c0 + tx] = t[tx][i];
    }
}

// ---------------- dwconv2 v2: (B,N,C) layout, float4 channels, XCD-contiguous swizzle ---
// xout = xin + conv3x3(xin) + bias. wt is (9, C) transposed taps.
// Swizzle: round-robin XCD dispatch => blk'=(blk&7)*per+(blk>>3) gives each XCD a
// contiguous run of tokens (exactly 4 whole images), making stencil reuse XCD-L2-local.
__global__ __launch_bounds__(256) void dwconv_bnc_v2(
    const float* __restrict__ xin, const float* __restrict__ wt,
    const float* __restrict__ bias, float* __restrict__ xout)
{
    const int nblk = (BN * 96) / 256;        // 9408
    const int per = nblk >> 3;               // 1176
    int blk = blockIdx.x;
    int blk2 = (blk & 7) * per + (blk >> 3);
    int g4 = blk2 * 256 + threadIdx.x;       // quad index: token*96 + c/4
    int q = g4 % 96;                         // c/4
    int r = g4 / 96;                         // b*NTOK + n
    int c = q * 4;
    int n = r % NTOK, b = r / NTOK;
    int h = n / WW, wcol = n % WW;
    const float4* base = (const float4*)(xin + (size_t)b * NTOK * CDIM);
    bool hm = h > 0, hp = h < HH - 1, wm = wcol > 0, wpv = wcol < WW - 1;

    float4 ctr = base[(size_t)n * 96 + q];
    float4 acc = {0.f, 0.f, 0.f, 0.f};
    fma4(acc, 1.f, ctr);   // placeholder overwritten below; (avoid uninit)
    acc.x = 0.f; acc.y = 0.f; acc.z = 0.f; acc.w = 0.f;

    const float4* w4 = (const float4*)wt;    // tap k at w4[k*96 + q]
#define TAP(k, cond, dn)                                            \
    if (cond) {                                                     \
        float4 vv = base[(size_t)(n + (dn)) * 96 + q];              \
        float4 ww = w4[(k) * 96 + q];                               \
        acc.x = fmaf(ww.x, vv.x, acc.x);                            \
        acc.y = fmaf(ww.y, vv.y, acc.y);                            \
        acc.z = fmaf(ww.z, vv.z, acc.z);                            \
        acc.w = fmaf(ww.w, vv.w, acc.w);                            \
    }
    TAP(0, hm && wm,   -WW - 1)
    TAP(1, hm,         -WW)
    TAP(2, hm && wpv,  -WW + 1)
    TAP(3, wm,         -1)
    { float4 ww = w4[4 * 96 + q];
      acc.x = fmaf(ww.x, ctr.x, acc.x); acc.y = fmaf(ww.y, ctr.y, acc.y);
      acc.z = fmaf(ww.z, ctr.z, acc.z); acc.w = fmaf(ww.w, ctr.w, acc.w); }
    TAP(5, wpv,        1)
    TAP(6, hp && wm,   WW - 1)
    TAP(7, hp,         WW)
    TAP(8, hp && wpv,  WW + 1)
#undef TAP
    float4 bb = *(const float4*)(bias + c);
    float4 outv;
    outv.x = ctr.x + acc.x + bb.x;
    outv.y = ctr.y + acc.y + bb.y;
    outv.z = ctr.z + acc.z + bb.z;
    outv.w = ctr.w + acc.w + bb.w;
    ((float4*)(xout))[g4] = outv;
}

// ---------------- LayerNorm over C=384, one wave per token; TO = float or bf16 ----------
template <typename TO>
__global__ __launch_bounds__(256) void layernorm_k(
    const float* __restrict__ in, const float* __restrict__ g,
    const float* __restrict__ b, TO* __restrict__ out)
{
    int wid = threadIdx.x >> 6;
    int lane = threadIdx.x & 63;
    size_t r = (size_t)blockIdx.x * 4 + wid;
    const float* row = in + r * CDIM;
    float v[6];
    float s = 0.f;
#pragma unroll
    for (int j = 0; j < 6; j++) { v[j] = row[lane + 64 * j]; s += v[j]; }
#pragma unroll
    for (int off = 32; off >= 1; off >>= 1) s += __shfl_xor(s, off);
    float mu = s * (1.f / CDIM);
    float q = 0.f;
#pragma unroll
    for (int j = 0; j < 6; j++) { float d = v[j] - mu; q += d * d; }
#pragma unroll
    for (int off = 32; off >= 1; off >>= 1) q += __shfl_xor(q, off);
    float rs = rsqrtf(q * (1.f / CDIM) + LN_EPS);
    TO* orow = out + r * CDIM;
#pragma unroll
    for (int j = 0; j < 6; j++) {
        int c = lane + 64 * j;
        stf(&orow[c], (v[j] - mu) * rs * g[c] + b[c]);
    }
}

// ---------------- MFMA GEMM v2 (128x128, BK=64, LDS-staged bf16 epilogue) -------------
template <int ACT, bool RES, typename TO>
__global__ __launch_bounds__(256) void gemm_mfma(
    const short* __restrict__ Abf, const short* __restrict__ Bw,
    const float* __restrict__ bias, const float* __restrict__ res,
    TO* __restrict__ Co, int K, int M)
{
    __shared__ short lds[16896];          // 33 KB: staging As|Bs, epilogue Cs
    short* As = lds;
    short* Bs = lds + 8192;
    const int tid = threadIdx.x;
    const int wid = tid >> 6, lane = tid & 63;
    const int wrow = wid >> 1, wcol = wid & 1;
    const int quad = lane >> 4, lr = lane & 15;
    const int r0 = blockIdx.y * 128, m0 = blockIdx.x * 128;

    const int srow = lane >> 3;
    const int sg   = (lane & 7) ^ srow;
    const short* gA = Abf + (size_t)(r0 + wid * 32 + srow) * K + sg * 8;
    const short* gB = Bw  + (size_t)(m0 + wid * 32 + srow) * K + sg * 8;
    short* lA = As + wid * 2048;
    short* lB = Bs + wid * 2048;

    int fAoff[4], fBoff[4];
#pragma unroll
    for (int i = 0; i < 4; i++) {
        fAoff[i] = (wrow * 64 + i * 16 + lr) * 64;
        fBoff[i] = (wcol * 64 + i * 16 + lr) * 64;
    }
    const int slot0 = ((0 + quad) ^ (lr & 7)) * 8;
    const int slot1 = ((4 + quad) ^ (lr & 7)) * 8;

    f32x4 acc[4][4] = {};

    for (int k0 = 0; k0 < K; k0 += 64) {
#pragma unroll
        for (int k = 0; k < 4; k++) {
            gload16(gA + k0 + (size_t)k * 8 * K, lA + k * 512);
            gload16(gB + k0 + (size_t)k * 8 * K, lB + k * 512);
        }
        __syncthreads();
#pragma unroll
        for (int s = 0; s < 2; s++) {
            const int so = s ? slot1 : slot0;
            bf16x8 av[4], bv[4];
#pragma unroll
            for (int i = 0; i < 4; i++) {
                av[i] = *(const bf16x8*)(As + fAoff[i] + so);
                bv[i] = *(const bf16x8*)(Bs + fBoff[i] + so);
            }
#pragma unroll
            for (int i = 0; i < 4; i++)
#pragma unroll
                for (int j = 0; j < 4; j++)
                    acc[i][j] = __builtin_amdgcn_mfma_f32_16x16x32_bf16(
                        av[i], bv[j], acc[i][j], 0, 0, 0);
        }
        __syncthreads();
    }

    if constexpr (sizeof(TO) == 4) {
#pragma unroll
        for (int i = 0; i < 4; i++) {
            int gr = r0 + wrow * 64 + i * 16 + quad * 4;
#pragma unroll
            for (int j = 0; j < 4; j++) {
                int gc = m0 + wcol * 64 + j * 16 + lr;
                float bb = bias ? bias[gc] : 0.f;
#pragma unroll
                for (int rr = 0; rr < 4; rr++) {
                    size_t idx = (size_t)(gr + rr) * M + gc;
                    float v = acc[i][j][rr] + bb;
                    if (RES) v += res[idx];
                    if (ACT == 1) v = gelu_f(v);
                    stf((float*)&Co[idx], v);
                }
            }
        }
    } else {
        short* Cs = lds;
#pragma unroll
        for (int i = 0; i < 4; i++) {
            int lrow = wrow * 64 + i * 16 + quad * 4;
#pragma unroll
            for (int j = 0; j < 4; j++) {
                int lcol = wcol * 64 + j * 16 + lr;
                float bb = bias ? bias[m0 + lcol] : 0.f;
#pragma unroll
                for (int rr = 0; rr < 4; rr++) {
                    float v = acc[i][j][rr] + bb;
                    if (ACT == 1) v = gelu_f(v);
                    Cs[(lrow + rr) * 132 + lcol] = f2bs(v);
                }
            }
        }
        __syncthreads();
        short* co = (short*)Co;
#pragma unroll
        for (int s = 0; s < 16; s++) {
            int row = s * 8 + (tid >> 5);
            int seg = tid & 31;
            uint2 vv = *(const uint2*)(Cs + row * 132 + seg * 4);
            *(uint2*)(co + (size_t)(r0 + row) * M + m0 + seg * 4) = vv;
        }
    }
}

// ---------------- channel attention: attn[b,h,d,e] = softmax_e(SCALE * sum_n k*v) ------
__global__ __launch_bounds__(256) void attn_k(
    const bf16* __restrict__ qkv, float* __restrict__ attn)
{
    int bh = blockIdx.x;
    int b = bh / NHEADS, h = bh % NHEADS;
    __shared__ float ks[64][32];
    __shared__ float vs[64][32];
    __shared__ float sm[32][33];
    int tid = threadIdx.x;
    int d = tid >> 3, e0 = (tid & 7) * 4;
    float acc[4] = {0.f, 0.f, 0.f, 0.f};
    for (int n0 = 0; n0 < NTOK; n0 += 64) {
#pragma unroll
        for (int i = 0; i < 8; i++) {
            int idx = tid + i * 256;
            int nn = idx >> 5, cc = idx & 31;
            int n = n0 + nn;
            float kv = 0.f, vv = 0.f;
            if (n < NTOK) {
                size_t base = ((size_t)b * NTOK + n) * (3 * CDIM);
                kv = ATT_SCALE * __bfloat162float(qkv[base + CDIM + h * HDIM + cc]);
                vv = __bfloat162float(qkv[base + 2 * CDIM + h * HDIM + cc]);
            }
            ks[nn][cc] = kv; vs[nn][cc] = vv;
        }
        __syncthreads();
#pragma unroll 8
        for (int nn = 0; nn < 64; nn++) {
            float kd = ks[nn][d];
#pragma unroll
            for (int j = 0; j < 4; j++) acc[j] += kd * vs[nn][e0 + j];
        }
        __syncthreads();
    }
#pragma unroll
    for (int j = 0; j < 4; j++) sm[d][e0 + j] = acc[j];
    __syncthreads();
    if (tid < 32) {
        float mx = -1e30f;
#pragma unroll
        for (int e = 0; e < 32; e++) mx = fmaxf(mx, sm[tid][e]);
        float ssum = 0.f;
        float ex[32];
#pragma unroll
        for (int e = 0; e < 32; e++) { ex[e] = expf(sm[tid][e] - mx); ssum += ex[e]; }
        float inv = 1.f / ssum;
        float* arow = attn + ((size_t)bh * 32 + tid) * 32;
#pragma unroll
        for (int e = 0; e < 32; e++) arow[e] = ex[e] * inv;
    }
}

// ---------------- apply attention v2: attn row in registers, 8-token staged chunks -----
__global__ __launch_bounds__(384) void apply_attn_k(
    const bf16* __restrict__ qkv, const float* __restrict__ attn,
    bf16* __restrict__ out)
{
    int b = blockIdx.x;
    int chunk = blockIdx.y;            // 14 chunks of 56 tokens
    int tid = threadIdx.x;             // 0..383
    int h = tid >> 5;
    __shared__ float qs[8][CDIM];
    float at[32];
    const float4* ap = (const float4*)(attn + ((size_t)(b * NHEADS) * 32 + tid) * 32);
#pragma unroll
    for (int e4 = 0; e4 < 8; e4++) {
        float4 v = ap[e4];
        at[e4 * 4 + 0] = v.x; at[e4 * 4 + 1] = v.y;
        at[e4 * 4 + 2] = v.z; at[e4 * 4 + 3] = v.w;
    }
    int nbase = chunk * 56;
    for (int t0 = 0; t0 < 56; t0 += 8) {
        __syncthreads();
#pragma unroll
        for (int i = 0; i < 8; i++) {
            int n = nbase + t0 + i;
            qs[i][tid] = __bfloat162float(qkv[((size_t)b * NTOK + n) * (3 * CDIM) + tid]);
        }
        __syncthreads();
#pragma unroll
        for (int i = 0; i < 8; i++) {
            const float* qrow = &qs[i][h * 32];
            float s = 0.f;
#pragma unroll
            for (int e = 0; e < 32; e++) s += at[e] * qrow[e];
            int n = nbase + t0 + i;
            out[((size_t)b * NTOK + n) * CDIM + tid] = __float2bfloat16(s);
        }
    }
}

// ---------------- final transpose: (B,N,C) -> (B,C,H,W) ----------------
__global__ __launch_bounds__(256) void transpose_out(
    const float* __restrict__ in, float* __restrict__ out)
{
    __shared__ float t[32][33];
    int b = blockIdx.z;
    int n0 = blockIdx.y * 32;
    int c0 = blockIdx.x * 32;
    int tx = threadIdx.x, ty = threadIdx.y;   // 32 x 8
    for (int i = ty; i < 32; i += 8) {
        int n = n0 + i;
        if (n < NTOK) t[i][tx] = in[((size_t)b * NTOK + n) * CDIM + c0 + tx];
    }
    __syncthreads();
    for (int i = ty; i < 32; i += 8) {
        int c = c0 + i;
        int n = n0 + tx;
        if (n < NTOK) out[((size_t)b * CDIM + c) * NTOK + n] = t[tx][i];
    }
}

extern "C" void kernel_launch(void* const* d_in, const int* in_sizes, int n_in,
                              void* d_out, int out_size, void* d_ws, size_t ws_size,
                              hipStream_t stream) {
    const float* x      = (const float*)d_in[0];
    const float* cpe1_w = (const float*)d_in[1];
    const float* cpe1_b = (const float*)d_in[2];
    const float* n1g    = (const float*)d_in[3];
    const float* n1b    = (const float*)d_in[4];
    const float* qkv_w  = (const float*)d_in[5];
    const float* proj_w = (const float*)d_in[6];
    const float* proj_b = (const float*)d_in[7];
    const float* cpe2_w = (const float*)d_in[8];
    const float* cpe2_b = (const float*)d_in[9];
    const float* n2g    = (const float*)d_in[10];
    const float* n2b    = (const float*)d_in[11];
    const float* fc1_w  = (const float*)d_in[12];
    const float* fc1_b  = (const float*)d_in[13];
    const float* fc2_w  = (const float*)d_in[14];
    const float* fc2_b  = (const float*)d_in[15];

    const size_t A = (size_t)BN * CDIM;        // 9,633,792
    const size_t HA = A / 2;

    // bf16 weights contiguous at front of ws
    bf16* wqkv  = (bf16*)d_ws;                 // 442368
    bf16* wproj = wqkv + 442368;               // 147456
    bf16* wfc1  = wproj + 147456;              // 589824
    bf16* wfc2  = wfc1 + 589824;               // 589824
    float* base = (float*)d_ws + 884736;

    float* xt        = base;                   // [0, A)        residual stream
    bf16*  curb      = (bf16*)(base + A);      // [A, 1.5A)     LN1 out (bf16)
    bf16*  ylnb      = (bf16*)(base + A);      // phase-2 reuse LN2 out (bf16)
    bf16*  qkvb      = (bf16*)(base + A + HA); // [1.5A, 3A)    qkv (bf16, 3A elems)
    float* x3        = base + A + HA;          // phase-2 reuse [1.5A, 2.5A)
    bf16*  h1        = (bf16*)(base + A + HA + A); // [2.5A, 4.5A) fc1 out (bf16)
    float* attnm     = base + 3 * A;           // [3A, +393216)
    bf16*  attn_outb = (bf16*)(base + 3 * A + 393216);
    float* finalb    = base;                   // xt region reuse
    float* xconv     = base + (A * 7) / 2;     // [3.5A, 4.5A)  dwconv1 NCHW temp
    float* cpe2_wt   = base + (A * 9) / 2;     // [4.5A, +3456) transposed taps

    // 0. weight conversion fp32 -> bf16 (single launch) + cpe2 tap transpose
    f2b4_k<<<1769472 / 256, 256, 0, stream>>>(qkv_w, proj_w, fc1_w, fc2_w, wqkv);
    wtr_k<<<14, 256, 0, stream>>>(cpe2_w, cpe2_wt);

    // 1a. cpe1 + residual in NCHW (coalesced, LDS-planed)
    dwconv_nchw_plane<<<BBATCH * CDIM, 256, 0, stream>>>(x, cpe1_w, cpe1_b, xconv);
    // 1b. transpose (B,C,N) -> (B,N,C)
    transpose_in<<<dim3(CDIM / 32, (NTOK + 31) / 32, BBATCH), dim3(32, 8), 0, stream>>>(
        xconv, xt);
    // 2. LN1 -> bf16
    layernorm_k<bf16><<<BN / 4, 256, 0, stream>>>(xt, n1g, n1b, curb);
    // 3. qkv GEMM (bf16 MFMA, out bf16)
    gemm_mfma<0, false, bf16><<<dim3(1152 / 128, BN / 128), 256, 0, stream>>>(
        (const short*)curb, (const short*)wqkv, nullptr, nullptr, qkvb, 384, 1152);
    // 4. channel attention matrices + softmax
    attn_k<<<BBATCH * NHEADS, 256, 0, stream>>>(qkvb, attnm);
    // 5. apply attention to q (out bf16)
    apply_attn_k<<<dim3(BBATCH, 14), 384, 0, stream>>>(qkvb, attnm, attn_outb);
    // 6. proj GEMM + bias + residual (in-place into xt)
    gemm_mfma<0, true, float><<<dim3(384 / 128, BN / 128), 256, 0, stream>>>(
        (const short*)attn_outb, (const short*)wproj, proj_b, xt, xt, 384, 384);
    // 7. cpe2 + residual in (B,N,C)  — XCD-swizzled, float4
    dwconv_bnc_v2<<<(BN * 96) / 256, 256, 0, stream>>>(xt, cpe2_wt, cpe2_b, x3);
    // 8. LN2 -> bf16
    layernorm_k<bf16><<<BN / 4, 256, 0, stream>>>(x3, n2g, n2b, ylnb);
    // 9. fc1 + bias + GELU (out bf16)
    gemm_mfma<1, false, bf16><<<dim3(1536 / 128, BN / 128), 256, 0, stream>>>(
        (const short*)ylnb, (const short*)wfc1, fc1_b, nullptr, h1, 384, 1536);
    // 10. fc2 + bias + residual(x3)
    gemm_mfma<0, true, float><<<dim3(384 / 128, BN / 128), 256, 0, stream>>>(
        (const short*)h1, (const short*)wfc2, fc2_b, x3, finalb, 1536, 384);
    // 11. (B,N,C) -> (B,C,H,W)
    transpose_out<<<dim3(CDIM / 32, (NTOK + 31) / 32, BBATCH), dim3(32, 8), 0, stream>>>(
        finalb, (float*)d_out);
}

// Round 6
// 468.194 us; speedup vs baseline: 5.2456x; 1.0658x over previous
//
#include <hip/hip_runtime.h>
#include <hip/hip_bf16.h>

#define CDIM 384
#define NHEADS 12
#define HDIM 32
#define HIDDEN 1536
#define BBATCH 32
#define HH 28
#define WW 28
#define NTOK 784
#define BN (BBATCH * NTOK)   // 25088
#define LN_EPS 1e-5f
#define ATT_SCALE 0.17677669529663687f
#define YTILES 196           // BN / 128
#define PERXCD 25            // ceil(YTILES / 8)

typedef __hip_bfloat16 bf16;
typedef __attribute__((ext_vector_type(8))) short bf16x8;
typedef __attribute__((ext_vector_type(4))) float f32x4;

__device__ __forceinline__ float ldf(const float* p) { return *p; }
__device__ __forceinline__ float ldf(const bf16* p) { return __bfloat162float(*p); }
__device__ __forceinline__ void stf(float* p, float v) { *p = v; }
__device__ __forceinline__ void stf(bf16* p, float v) { *p = __float2bfloat16(v); }

__device__ __forceinline__ short f2bs(float v) {
    bf16 t = __float2bfloat16(v);
    return *reinterpret_cast<short*>(&t);
}

// tanh-form GELU via sigmoid; max |diff| vs exact ~3e-4, well inside tolerance.
__device__ __forceinline__ float gelu_f(float x) {
    float u = x * (0.7978845608f + 0.0356774081f * x * x);
    float e = __expf(-2.f * u);
    return x / (1.f + e);
}

__device__ __forceinline__ void gload16(const void* g, void* l) {
    __builtin_amdgcn_global_load_lds(
        (const __attribute__((address_space(1))) unsigned int*)g,
        (__attribute__((address_space(3))) unsigned int*)l, 16, 0, 0);
}

// ---------------- fp32 -> bf16 weight conversion (all 4 weights, one launch) ------------
__global__ __launch_bounds__(256) void f2b4_k(
    const float* __restrict__ w0, const float* __restrict__ w1,
    const float* __restrict__ w2, const float* __restrict__ w3,
    bf16* __restrict__ dst)
{
    int i = blockIdx.x * 256 + threadIdx.x;   // 0..1769471, dst regions contiguous
    const float* src; int off;
    if (i < 442368)       { src = w0; off = i; }
    else if (i < 589824)  { src = w1; off = i - 442368; }
    else if (i < 1179648) { src = w2; off = i - 589824; }
    else                  { src = w3; off = i - 1179648; }
    dst[i] = __float2bfloat16(src[off]);
}

// ---------------- transpose cpe2 weights (C,9) -> (9,C) ----------------
__global__ __launch_bounds__(256) void wtr_k(const float* __restrict__ w,
                                             float* __restrict__ wt)
{
    int i = blockIdx.x * 256 + threadIdx.x;   // 0..3455
    if (i < 9 * CDIM) {
        int k = i / CDIM, c = i % CDIM;
        wt[i] = w[c * 9 + k];
    }
}

// ---------------- dwconv1 pass A: per-(b,c) plane conv in NCHW, coalesced ----------------
__global__ __launch_bounds__(256) void dwconv_nchw_plane(
    const float* __restrict__ x, const float* __restrict__ w,
    const float* __restrict__ bias, float* __restrict__ y)
{
    __shared__ float sm[NTOK];
    int bc = blockIdx.x;                    // b*CDIM + c
    int c = bc % CDIM;
    const float* xp = x + (size_t)bc * NTOK;
    int tid = threadIdx.x;
#pragma unroll
    for (int i = 0; i < 4; i++) {
        int p = tid + i * 256;
        if (p < NTOK) sm[p] = xp[p];
    }
    __syncthreads();
    const float* wp = w + c * 9;
    float w00 = wp[0], w01 = wp[1], w02 = wp[2];
    float w10 = wp[3], w11 = wp[4], w12 = wp[5];
    float w20 = wp[6], w21 = wp[7], w22 = wp[8];
    float bc_ = bias[c];
    float* yp = y + (size_t)bc * NTOK;
#pragma unroll
    for (int i = 0; i < 4; i++) {
        int p = tid + i * 256;
        if (p >= NTOK) break;
        int h = p / WW, wcol = p % WW;
        bool hm = h > 0, hp = h < HH - 1, wm = wcol > 0, wpv = wcol < WW - 1;
        float s = w11 * sm[p];
        if (hm)        s += w01 * sm[p - WW];
        if (hp)        s += w21 * sm[p + WW];
        if (wm)        s += w10 * sm[p - 1];
        if (wpv)       s += w12 * sm[p + 1];
        if (hm && wm)  s += w00 * sm[p - WW - 1];
        if (hm && wpv) s += w02 * sm[p - WW + 1];
        if (hp && wm)  s += w20 * sm[p + WW - 1];
        if (hp && wpv) s += w22 * sm[p + WW + 1];
        yp[p] = sm[p] + s + bc_;
    }
}

// ---------------- dwconv1 pass B: transpose (B,C,N) -> (B,N,C) ----------------
__global__ __launch_bounds__(256) void transpose_in(
    const float* __restrict__ in, float* __restrict__ out)
{
    __shared__ float t[32][33];
    int b = blockIdx.z;
    int n0 = blockIdx.y * 32;
    int c0 = blockIdx.x * 32;
    int tx = threadIdx.x, ty = threadIdx.y;   // 32 x 8
    for (int i = ty; i < 32; i += 8) {
        int n = n0 + tx;
        if (n < NTOK) t[i][tx] = in[((size_t)b * CDIM + c0 + i) * NTOK + n];
    }
    __syncthreads();
    for (int i = ty; i < 32; i += 8) {
        int n = n0 + i;
        if (n < NTOK) out[((size_t)b * NTOK + n) * CDIM + c0 + tx] = t[tx][i];
    }
}

// ---------------- dwconv2 v2: (B,N,C) layout, float4 channels, XCD-contiguous swizzle ---
__global__ __launch_bounds__(256) void dwconv_bnc_v2(
    const float* __restrict__ xin, const float* __restrict__ wt,
    const float* __restrict__ bias, float* __restrict__ xout)
{
    const int nblk = (BN * 96) / 256;        // 9408
    const int per = nblk >> 3;               // 1176
    int blk = blockIdx.x;
    int blk2 = (blk & 7) * per + (blk >> 3);
    int g4 = blk2 * 256 + threadIdx.x;       // quad index: token*96 + c/4
    int q = g4 % 96;                         // c/4
    int r = g4 / 96;                         // b*NTOK + n
    int c = q * 4;
    int n = r % NTOK, b = r / NTOK;
    int h = n / WW, wcol = n % WW;
    const float4* base = (const float4*)(xin + (size_t)b * NTOK * CDIM);
    bool hm = h > 0, hp = h < HH - 1, wm = wcol > 0, wpv = wcol < WW - 1;

    float4 ctr = base[(size_t)n * 96 + q];
    float4 acc = {0.f, 0.f, 0.f, 0.f};

    const float4* w4 = (const float4*)wt;    // tap k at w4[k*96 + q]
#define TAP(k, cond, dn)                                            \
    if (cond) {                                                     \
        float4 vv = base[(size_t)(n + (dn)) * 96 + q];              \
        float4 ww = w4[(k) * 96 + q];                               \
        acc.x = fmaf(ww.x, vv.x, acc.x);                            \
        acc.y = fmaf(ww.y, vv.y, acc.y);                            \
        acc.z = fmaf(ww.z, vv.z, acc.z);                            \
        acc.w = fmaf(ww.w, vv.w, acc.w);                            \
    }
    TAP(0, hm && wm,   -WW - 1)
    TAP(1, hm,         -WW)
    TAP(2, hm && wpv,  -WW + 1)
    TAP(3, wm,         -1)
    { float4 ww = w4[4 * 96 + q];
      acc.x = fmaf(ww.x, ctr.x, acc.x); acc.y = fmaf(ww.y, ctr.y, acc.y);
      acc.z = fmaf(ww.z, ctr.z, acc.z); acc.w = fmaf(ww.w, ctr.w, acc.w); }
    TAP(5, wpv,        1)
    TAP(6, hp && wm,   WW - 1)
    TAP(7, hp,         WW)
    TAP(8, hp && wpv,  WW + 1)
#undef TAP
    float4 bb = *(const float4*)(bias + c);
    float4 outv;
    outv.x = ctr.x + acc.x + bb.x;
    outv.y = ctr.y + acc.y + bb.y;
    outv.z = ctr.z + acc.z + bb.z;
    outv.w = ctr.w + acc.w + bb.w;
    ((float4*)(xout))[g4] = outv;
}

// ---------------- LayerNorm over C=384, one wave per token; TO = float or bf16 ----------
template <typename TO>
__global__ __launch_bounds__(256) void layernorm_k(
    const float* __restrict__ in, const float* __restrict__ g,
    const float* __restrict__ b, TO* __restrict__ out)
{
    int wid = threadIdx.x >> 6;
    int lane = threadIdx.x & 63;
    size_t r = (size_t)blockIdx.x * 4 + wid;
    const float* row = in + r * CDIM;
    float v[6];
    float s = 0.f;
#pragma unroll
    for (int j = 0; j < 6; j++) { v[j] = row[lane + 64 * j]; s += v[j]; }
#pragma unroll
    for (int off = 32; off >= 1; off >>= 1) s += __shfl_xor(s, off);
    float mu = s * (1.f / CDIM);
    float q = 0.f;
#pragma unroll
    for (int j = 0; j < 6; j++) { float d = v[j] - mu; q += d * d; }
#pragma unroll
    for (int off = 32; off >= 1; off >>= 1) q += __shfl_xor(q, off);
    float rs = rsqrtf(q * (1.f / CDIM) + LN_EPS);
    TO* orow = out + r * CDIM;
#pragma unroll
    for (int j = 0; j < 6; j++) {
        int c = lane + 64 * j;
        stf(&orow[c], (v[j] - mu) * rs * g[c] + b[c]);
    }
}

// ---------------- MFMA GEMM v3: XCD-exclusive y-panels + LDS double-buffer -------------
// 128x128 tile, 4 waves, BK=64. 1D grid of 8*PERXCD*NX blocks; round-robin XCD
// dispatch (xcd = id&7) => XCD k processes y-tiles [k*PERXCD, ...) with all NX
// column-blocks consecutive => A panel fetched once per XCD, weights L2-resident.
// Double-buffered staging: single barrier per K-iter; tile k+1 loads overlap tile
// k's 32 MFMA. bf16 output via LDS-staged full-line epilogue.
template <int ACT, bool RES, typename TO>
__global__ __launch_bounds__(256) void gemm_mfma(
    const short* __restrict__ Abf, const short* __restrict__ Bw,
    const float* __restrict__ bias, const float* __restrict__ res,
    TO* __restrict__ Co, int K, int M, int NX)
{
    int id = blockIdx.x;
    int xcd = id & 7, slot = id >> 3;
    int yloc = slot / NX, xx = slot - yloc * NX;
    int y = xcd * PERXCD + yloc;
    if (y >= YTILES) return;

    __shared__ short lds[32768];          // 64 KB: 2 x (As 8K | Bs 8K) shorts
    const int tid = threadIdx.x;
    const int wid = tid >> 6, lane = tid & 63;
    const int wrow = wid >> 1, wcol = wid & 1;
    const int quad = lane >> 4, lr = lane & 15;
    const int r0 = y * 128, m0 = xx * 128;

    const int srow = lane >> 3;
    const int sg   = (lane & 7) ^ srow;
    const short* gA = Abf + (size_t)(r0 + wid * 32 + srow) * K + sg * 8;
    const short* gB = Bw  + (size_t)(m0 + wid * 32 + srow) * K + sg * 8;

    auto stage = [&](int k0, int p) {
        short* lA = lds + p * 16384 + wid * 2048;
        short* lB = lds + p * 16384 + 8192 + wid * 2048;
#pragma unroll
        for (int k = 0; k < 4; k++) {
            gload16(gA + k0 + (size_t)k * 8 * K, lA + k * 512);
            gload16(gB + k0 + (size_t)k * 8 * K, lB + k * 512);
        }
    };

    int fAoff[4], fBoff[4];
#pragma unroll
    for (int i = 0; i < 4; i++) {
        fAoff[i] = (wrow * 64 + i * 16 + lr) * 64;
        fBoff[i] = (wcol * 64 + i * 16 + lr) * 64;
    }
    const int slot0 = ((0 + quad) ^ (lr & 7)) * 8;
    const int slot1 = ((4 + quad) ^ (lr & 7)) * 8;

    f32x4 acc[4][4] = {};

    stage(0, 0);
    int p = 0;
    for (int k0 = 0; k0 < K; k0 += 64) {
        __syncthreads();                  // drains buf p loads (vmcnt0 before barrier)
        if (k0 + 64 < K) stage(k0 + 64, p ^ 1);   // overlaps with compute below
        const short* As = lds + p * 16384;
        const short* Bs = As + 8192;
#pragma unroll
        for (int s = 0; s < 2; s++) {
            const int so = s ? slot1 : slot0;
            bf16x8 av[4], bv[4];
#pragma unroll
            for (int i = 0; i < 4; i++) {
                av[i] = *(const bf16x8*)(As + fAoff[i] + so);
                bv[i] = *(const bf16x8*)(Bs + fBoff[i] + so);
            }
#pragma unroll
            for (int i = 0; i < 4; i++)
#pragma unroll
                for (int j = 0; j < 4; j++)
                    acc[i][j] = __builtin_amdgcn_mfma_f32_16x16x32_bf16(
                        av[i], bv[j], acc[i][j], 0, 0, 0);
        }
        p ^= 1;
    }

    if constexpr (sizeof(TO) == 4) {
#pragma unroll
        for (int i = 0; i < 4; i++) {
            int gr = r0 + wrow * 64 + i * 16 + quad * 4;
#pragma unroll
            for (int j = 0; j < 4; j++) {
                int gc = m0 + wcol * 64 + j * 16 + lr;
                float bb = bias ? bias[gc] : 0.f;
#pragma unroll
                for (int rr = 0; rr < 4; rr++) {
                    size_t idx = (size_t)(gr + rr) * M + gc;
                    float v = acc[i][j][rr] + bb;
                    if (RES) v += res[idx];
                    if (ACT == 1) v = gelu_f(v);
                    stf((float*)&Co[idx], v);
                }
            }
        }
    } else {
        __syncthreads();                  // all LDS reads done before Cs overwrite
        short* Cs = lds;
#pragma unroll
        for (int i = 0; i < 4; i++) {
            int lrow = wrow * 64 + i * 16 + quad * 4;
#pragma unroll
            for (int j = 0; j < 4; j++) {
                int lcol = wcol * 64 + j * 16 + lr;
                float bb = bias ? bias[m0 + lcol] : 0.f;
#pragma unroll
                for (int rr = 0; rr < 4; rr++) {
                    float v = acc[i][j][rr] + bb;
                    if (ACT == 1) v = gelu_f(v);
                    Cs[(lrow + rr) * 132 + lcol] = f2bs(v);
                }
            }
        }
        __syncthreads();
        short* co = (short*)Co;
#pragma unroll
        for (int s = 0; s < 16; s++) {
            int row = s * 8 + (tid >> 5);
            int seg = tid & 31;
            uint2 vv = *(const uint2*)(Cs + row * 132 + seg * 4);
            *(uint2*)(co + (size_t)(r0 + row) * M + m0 + seg * 4) = vv;
        }
    }
}

// ---------------- channel attention: attn[b,h,d,e] = softmax_e(SCALE * sum_n k*v) ------
__global__ __launch_bounds__(256) void attn_k(
    const bf16* __restrict__ qkv, float* __restrict__ attn)
{
    int bh = blockIdx.x;
    int b = bh / NHEADS, h = bh % NHEADS;
    __shared__ float ks[64][32];
    __shared__ float vs[64][32];
    __shared__ float sm[32][33];
    int tid = threadIdx.x;
    int d = tid >> 3, e0 = (tid & 7) * 4;
    float acc[4] = {0.f, 0.f, 0.f, 0.f};
    for (int n0 = 0; n0 < NTOK; n0 += 64) {
#pragma unroll
        for (int i = 0; i < 8; i++) {
            int idx = tid + i * 256;
            int nn = idx >> 5, cc = idx & 31;
            int n = n0 + nn;
            float kv = 0.f, vv = 0.f;
            if (n < NTOK) {
                size_t base = ((size_t)b * NTOK + n) * (3 * CDIM);
                kv = ATT_SCALE * __bfloat162float(qkv[base + CDIM + h * HDIM + cc]);
                vv = __bfloat162float(qkv[base + 2 * CDIM + h * HDIM + cc]);
            }
            ks[nn][cc] = kv; vs[nn][cc] = vv;
        }
        __syncthreads();
#pragma unroll 8
        for (int nn = 0; nn < 64; nn++) {
            float kd = ks[nn][d];
#pragma unroll
            for (int j = 0; j < 4; j++) acc[j] += kd * vs[nn][e0 + j];
        }
        __syncthreads();
    }
#pragma unroll
    for (int j = 0; j < 4; j++) sm[d][e0 + j] = acc[j];
    __syncthreads();
    if (tid < 32) {
        float mx = -1e30f;
#pragma unroll
        for (int e = 0; e < 32; e++) mx = fmaxf(mx, sm[tid][e]);
        float ssum = 0.f;
        float ex[32];
#pragma unroll
        for (int e = 0; e < 32; e++) { ex[e] = expf(sm[tid][e] - mx); ssum += ex[e]; }
        float inv = 1.f / ssum;
        float* arow = attn + ((size_t)bh * 32 + tid) * 32;
#pragma unroll
        for (int e = 0; e < 32; e++) arow[e] = ex[e] * inv;
    }
}

// ---------------- apply attention v2: attn row in registers, 8-token staged chunks -----
__global__ __launch_bounds__(384) void apply_attn_k(
    const bf16* __restrict__ qkv, const float* __restrict__ attn,
    bf16* __restrict__ out)
{
    int b = blockIdx.x;
    int chunk = blockIdx.y;            // 14 chunks of 56 tokens
    int tid = threadIdx.x;             // 0..383
    int h = tid >> 5;
    __shared__ float qs[8][CDIM];
    float at[32];
    const float4* ap = (const float4*)(attn + ((size_t)(b * NHEADS) * 32 + tid) * 32);
#pragma unroll
    for (int e4 = 0; e4 < 8; e4++) {
        float4 v = ap[e4];
        at[e4 * 4 + 0] = v.x; at[e4 * 4 + 1] = v.y;
        at[e4 * 4 + 2] = v.z; at[e4 * 4 + 3] = v.w;
    }
    int nbase = chunk * 56;
    for (int t0 = 0; t0 < 56; t0 += 8) {
        __syncthreads();
#pragma unroll
        for (int i = 0; i < 8; i++) {
            int n = nbase + t0 + i;
            qs[i][tid] = __bfloat162float(qkv[((size_t)b * NTOK + n) * (3 * CDIM) + tid]);
        }
        __syncthreads();
#pragma unroll
        for (int i = 0; i < 8; i++) {
            const float* qrow = &qs[i][h * 32];
            float s = 0.f;
#pragma unroll
            for (int e = 0; e < 32; e++) s += at[e] * qrow[e];
            int n = nbase + t0 + i;
            out[((size_t)b * NTOK + n) * CDIM + tid] = __float2bfloat16(s);
        }
    }
}

// ---------------- final transpose: (B,N,C) -> (B,C,H,W) ----------------
__global__ __launch_bounds__(256) void transpose_out(
    const float* __restrict__ in, float* __restrict__ out)
{
    __shared__ float t[32][33];
    int b = blockIdx.z;
    int n0 = blockIdx.y * 32;
    int c0 = blockIdx.x * 32;
    int tx = threadIdx.x, ty = threadIdx.y;   // 32 x 8
    for (int i = ty; i < 32; i += 8) {
        int n = n0 + i;
        if (n < NTOK) t[i][tx] = in[((size_t)b * NTOK + n) * CDIM + c0 + tx];
    }
    __syncthreads();
    for (int i = ty; i < 32; i += 8) {
        int c = c0 + i;
        int n = n0 + tx;
        if (n < NTOK) out[((size_t)b * CDIM + c) * NTOK + n] = t[tx][i];
    }
}

extern "C" void kernel_launch(void* const* d_in, const int* in_sizes, int n_in,
                              void* d_out, int out_size, void* d_ws, size_t ws_size,
                              hipStream_t stream) {
    const float* x      = (const float*)d_in[0];
    const float* cpe1_w = (const float*)d_in[1];
    const float* cpe1_b = (const float*)d_in[2];
    const float* n1g    = (const float*)d_in[3];
    const float* n1b    = (const float*)d_in[4];
    const float* qkv_w  = (const float*)d_in[5];
    const float* proj_w = (const float*)d_in[6];
    const float* proj_b = (const float*)d_in[7];
    const float* cpe2_w = (const float*)d_in[8];
    const float* cpe2_b = (const float*)d_in[9];
    const float* n2g    = (const float*)d_in[10];
    const float* n2b    = (const float*)d_in[11];
    const float* fc1_w  = (const float*)d_in[12];
    const float* fc1_b  = (const float*)d_in[13];
    const float* fc2_w  = (const float*)d_in[14];
    const float* fc2_b  = (const float*)d_in[15];

    const size_t A = (size_t)BN * CDIM;        // 9,633,792
    const size_t HA = A / 2;

    // bf16 weights contiguous at front of ws
    bf16* wqkv  = (bf16*)d_ws;                 // 442368
    bf16* wproj = wqkv + 442368;               // 147456
    bf16* wfc1  = wproj + 147456;              // 589824
    bf16* wfc2  = wfc1 + 589824;               // 589824
    float* base = (float*)d_ws + 884736;

    float* xt        = base;                   // [0, A)        residual stream
    bf16*  curb      = (bf16*)(base + A);      // [A, 1.5A)     LN1 out (bf16)
    bf16*  ylnb      = (bf16*)(base + A);      // phase-2 reuse LN2 out (bf16)
    bf16*  qkvb      = (bf16*)(base + A + HA); // [1.5A, 3A)    qkv (bf16, 3A elems)
    float* x3        = base + A + HA;          // phase-2 reuse [1.5A, 2.5A)
    bf16*  h1        = (bf16*)(base + A + HA + A); // [2.5A, 4.5A) fc1 out (bf16)
    float* attnm     = base + 3 * A;           // [3A, +393216)
    bf16*  attn_outb = (bf16*)(base + 3 * A + 393216);
    float* finalb    = base;                   // xt region reuse
    float* xconv     = base + (A * 7) / 2;     // [3.5A, 4.5A)  dwconv1 NCHW temp
    float* cpe2_wt   = base + (A * 9) / 2;     // [4.5A, +3456) transposed taps

    const int GEMM_GRID3  = 8 * PERXCD * 3;    // 600
    const int GEMM_GRID9  = 8 * PERXCD * 9;    // 1800
    const int GEMM_GRID12 = 8 * PERXCD * 12;   // 2400

    // 0. weight conversion fp32 -> bf16 (single launch) + cpe2 tap transpose
    f2b4_k<<<1769472 / 256, 256, 0, stream>>>(qkv_w, proj_w, fc1_w, fc2_w, wqkv);
    wtr_k<<<14, 256, 0, stream>>>(cpe2_w, cpe2_wt);

    // 1a. cpe1 + residual in NCHW (coalesced, LDS-planed)
    dwconv_nchw_plane<<<BBATCH * CDIM, 256, 0, stream>>>(x, cpe1_w, cpe1_b, xconv);
    // 1b. transpose (B,C,N) -> (B,N,C)
    transpose_in<<<dim3(CDIM / 32, (NTOK + 31) / 32, BBATCH), dim3(32, 8), 0, stream>>>(
        xconv, xt);
    // 2. LN1 -> bf16
    layernorm_k<bf16><<<BN / 4, 256, 0, stream>>>(xt, n1g, n1b, curb);
    // 3. qkv GEMM (bf16 MFMA, out bf16)
    gemm_mfma<0, false, bf16><<<GEMM_GRID9, 256, 0, stream>>>(
        (const short*)curb, (const short*)wqkv, nullptr, nullptr, qkvb, 384, 1152, 9);
    // 4. channel attention matrices + softmax
    attn_k<<<BBATCH * NHEADS, 256, 0, stream>>>(qkvb, attnm);
    // 5. apply attention to q (out bf16)
    apply_attn_k<<<dim3(BBATCH, 14), 384, 0, stream>>>(qkvb, attnm, attn_outb);
    // 6. proj GEMM + bias + residual (in-place into xt)
    gemm_mfma<0, true, float><<<GEMM_GRID3, 256, 0, stream>>>(
        (const short*)attn_outb, (const short*)wproj, proj_b, xt, xt, 384, 384, 3);
    // 7. cpe2 + residual in (B,N,C)  — XCD-swizzled, float4
    dwconv_bnc_v2<<<(BN * 96) / 256, 256, 0, stream>>>(xt, cpe2_wt, cpe2_b, x3);
    // 8. LN2 -> bf16
    layernorm_k<bf16><<<BN / 4, 256, 0, stream>>>(x3, n2g, n2b, ylnb);
    // 9. fc1 + bias + GELU (out bf16)
    gemm_mfma<1, false, bf16><<<GEMM_GRID12, 256, 0, stream>>>(
        (const short*)ylnb, (const short*)wfc1, fc1_b, nullptr, h1, 384, 1536, 12);
    // 10. fc2 + bias + residual(x3)
    gemm_mfma<0, true, float><<<GEMM_GRID3, 256, 0, stream>>>(
        (const short*)h1, (const short*)wfc2, fc2_b, x3, finalb, 1536, 384, 3);
    // 11. (B,N,C) -> (B,C,H,W)
    transpose_out<<<dim3(CDIM / 32, (NTOK + 31) / 32, BBATCH), dim3(32, 8), 0, stream>>>(
        finalb, (float*)d_out);
}